// Round 1
// baseline (1068.908 us; speedup 1.0000x reference)
//
#include <hip/hip_runtime.h>
#include <math.h>

#define NB 16
#define NL 4096
#define ND 192
#define NH 384
#define NS 16
#define NTK 17
#define NIR 128
#define NR 24
#define NHH 64
#define NWW 64
#define NCHUNKS 32
#define CHUNKLEN 128
#define NTOK (NB*NL)

__device__ __forceinline__ float gelu_tanh(float x){
  return 0.5f*x*(1.0f + tanhf(0.7978845608028654f*(x + 0.044715f*x*x*x)));
}
__device__ __forceinline__ float softplus_f(float x){
  return (x > 20.0f) ? x : log1pf(expf(x));
}

// full_emb = embB(17x128) @ token_weight(128x16)
__global__ void k_emb(const float* __restrict__ embB, const float* __restrict__ tw,
                      float* __restrict__ fe){
  for (int o = threadIdx.x; o < NTK*NS; o += 256){
    int t = o / NS, s = o % NS;
    float acc = 0.f;
    for (int i = 0; i < NIR; ++i) acc += embB[t*NIR+i]*tw[i*NS+s];
    fe[o] = acc;
  }
}

// logits = hmid @ w2^T + b2 + gumbel ; idx = argmax (first occurrence)
__global__ __launch_bounds__(256) void k_argmax(const float* __restrict__ hmid,
    const float* __restrict__ w2, const float* __restrict__ b2,
    const float* __restrict__ gumbel, int* __restrict__ idx){
  int g = blockIdx.x*256 + threadIdx.x;
  float hm[64];
  const float4* hp = (const float4*)(hmid + (size_t)g*64);
  #pragma unroll
  for (int i = 0; i < 16; ++i){
    float4 v = hp[i];
    hm[i*4+0]=v.x; hm[i*4+1]=v.y; hm[i*4+2]=v.z; hm[i*4+3]=v.w;
  }
  float best = -INFINITY; int bi = 0;
  for (int c = 0; c < NTK; ++c){
    float s = b2[c] + gumbel[(size_t)g*NTK + c];
    #pragma unroll
    for (int j = 0; j < 64; ++j) s += hm[j]*w2[c*64+j];
    if (s > best){ best = s; bi = c; }
  }
  idx[g] = bi;
}

// stable counting sort per batch over 17 keys.
// rmap[b*NL+pos] = b*NL + original_token (== sort_idx as absolute row)
// inv [b*NL+orig] = pos
__global__ __launch_bounds__(256) void k_sort(const int* __restrict__ idx,
    int* __restrict__ rmap, int* __restrict__ inv){
  int b = blockIdx.x, t = threadIdx.x;
  __shared__ int hist[NTK][256];
  __shared__ int tot[NTK];
  __shared__ int keybase[NTK];
  int keys[16];
  const int* ip = idx + b*NL + t*16;
  #pragma unroll
  for (int i = 0; i < 16; ++i) keys[i] = ip[i];
  #pragma unroll
  for (int k = 0; k < NTK; ++k){
    int c = 0;
    #pragma unroll
    for (int i = 0; i < 16; ++i) c += (keys[i]==k) ? 1 : 0;
    hist[k][t] = c;
  }
  __syncthreads();
  if (t < NTK){
    int run = 0;
    for (int j = 0; j < 256; ++j){ int v = hist[t][j]; hist[t][j] = run; run += v; }
    tot[t] = run;
  }
  __syncthreads();
  if (t == 0){
    int base = 0;
    for (int k = 0; k < NTK; ++k){ keybase[k] = base; base += tot[k]; }
  }
  __syncthreads();
  #pragma unroll
  for (int i = 0; i < 16; ++i){
    int k = keys[i];
    int cb = 0;
    #pragma unroll
    for (int j = 0; j < 16; ++j) cb += (j < i && keys[j]==k) ? 1 : 0;
    int pos = keybase[k] + hist[k][t] + cb;
    rmap[b*NL + pos] = b*NL + t*16 + i;
    inv[b*NL + t*16 + i] = pos;
  }
}

// C(M x N) = A(M x K, lda) @ W(N x K, ldw)^T + bias, tiled 64x64x16, 4x4/thread.
// EPI: 0 none, 1 gelu, 2 softplus, 3 row-scatter via remap
template<int EPI>
__global__ __launch_bounds__(256) void k_gemm(const float* __restrict__ A, int lda,
    const float* __restrict__ W, int ldw, const float* __restrict__ bias,
    float* __restrict__ C, int ldc, int N, int K, const int* __restrict__ remap){
  __shared__ float As[16][68];
  __shared__ float Ws[16][68];
  int tid = threadIdx.x;
  int m0 = blockIdx.x*64, n0 = blockIdx.y*64;
  int tx = tid & 15, ty = tid >> 4;
  int srow = tid >> 2, skseg = (tid & 3)*4;
  float acc[4][4] = {};
  for (int k0 = 0; k0 < K; k0 += 16){
    {
      const float* ap = A + (size_t)(m0+srow)*lda + k0 + skseg;
      float4 v;
      if (k0 + skseg + 3 < K) v = *(const float4*)ap;
      else {
        v.x = (k0+skseg+0 < K)?ap[0]:0.f; v.y = (k0+skseg+1 < K)?ap[1]:0.f;
        v.z = (k0+skseg+2 < K)?ap[2]:0.f; v.w = (k0+skseg+3 < K)?ap[3]:0.f;
      }
      As[skseg+0][srow]=v.x; As[skseg+1][srow]=v.y;
      As[skseg+2][srow]=v.z; As[skseg+3][srow]=v.w;
    }
    {
      float4 v = {0.f,0.f,0.f,0.f};
      if (n0 + srow < N){
        const float* wp = W + (size_t)(n0+srow)*ldw + k0 + skseg;
        if (k0 + skseg + 3 < K) v = *(const float4*)wp;
        else {
          v.x = (k0+skseg+0 < K)?wp[0]:0.f; v.y = (k0+skseg+1 < K)?wp[1]:0.f;
          v.z = (k0+skseg+2 < K)?wp[2]:0.f; v.w = (k0+skseg+3 < K)?wp[3]:0.f;
        }
      }
      Ws[skseg+0][srow]=v.x; Ws[skseg+1][srow]=v.y;
      Ws[skseg+2][srow]=v.z; Ws[skseg+3][srow]=v.w;
    }
    __syncthreads();
    #pragma unroll
    for (int kk = 0; kk < 16; ++kk){
      float4 av = *(const float4*)&As[kk][ty*4];
      float4 wv = *(const float4*)&Ws[kk][tx*4];
      acc[0][0] += av.x*wv.x; acc[0][1] += av.x*wv.y;
      acc[0][2] += av.x*wv.z; acc[0][3] += av.x*wv.w;
      acc[1][0] += av.y*wv.x; acc[1][1] += av.y*wv.y;
      acc[1][2] += av.y*wv.z; acc[1][3] += av.y*wv.w;
      acc[2][0] += av.z*wv.x; acc[2][1] += av.z*wv.y;
      acc[2][2] += av.z*wv.z; acc[2][3] += av.z*wv.w;
      acc[3][0] += av.w*wv.x; acc[3][1] += av.w*wv.y;
      acc[3][2] += av.w*wv.z; acc[3][3] += av.w*wv.w;
    }
    __syncthreads();
  }
  #pragma unroll
  for (int i = 0; i < 4; ++i){
    int m = m0 + ty*4 + i;
    int orow = (EPI==3) ? remap[m] : m;
    #pragma unroll
    for (int j = 0; j < 4; ++j){
      int n = n0 + tx*4 + j;
      if (n < N){
        float v = acc[i][j] + (bias ? bias[n] : 0.f);
        if (EPI==1) v = gelu_tanh(v);
        if (EPI==2) v = softplus_f(v);
        C[(size_t)orow*ldc + n] = v;
      }
    }
  }
}

// depthwise 3x3 SAME conv + bias -> sigmoid gate; scatter rows to sorted order via inv
__global__ __launch_bounds__(256) void k_cpe(const float* __restrict__ xi,
    const float* __restrict__ cw, const float* __restrict__ cb,
    const int* __restrict__ inv, float* __restrict__ us){
  int bl = blockIdx.x;
  int cg = bl & 3;
  int xt = (bl>>2) & 7;
  int yt = (bl>>5) & 7;
  int b  = bl >> 8;
  __shared__ float tile[10*10*96];
  int c0 = cg*96;
  for (int p = threadIdx.x; p < 10*10*96; p += 256){
    int c = p % 96; int xx = (p/96) % 10; int yy = p/960;
    int gy = yt*8 + yy - 1, gx = xt*8 + xx - 1;
    float v = 0.f;
    if (gy >= 0 && gy < NHH && gx >= 0 && gx < NWW)
      v = xi[((size_t)(b*NL + gy*NWW + gx))*NH + c0 + c];
    tile[p] = v;
  }
  __syncthreads();
  for (int p = threadIdx.x; p < 8*8*96; p += 256){
    int c = p % 96; int xx = (p/96) % 8; int yy = p/768;
    int ch = c0 + c;
    float acc = cb[ch];
    #pragma unroll
    for (int dy = 0; dy < 3; ++dy)
      #pragma unroll
      for (int dx = 0; dx < 3; ++dx)
        acc += tile[((yy+dy)*10 + (xx+dx))*96 + c] * cw[ch*9 + dy*3 + dx];
    float center = tile[((yy+1)*10 + (xx+1))*96 + c];
    float gate = 1.f/(1.f + expf(-acc));
    int l = (yt*8+yy)*NWW + xt*8+xx;
    int pos = inv[b*NL + l];
    us[((size_t)(b*NL + pos))*NH + ch] = center*gate;
  }
}

// split x_dbl into Bs, Cs (+ prompt via unsorted idx, faithful to reference)
__global__ __launch_bounds__(256) void k_bc(const float* __restrict__ dbl,
    const int* __restrict__ idx, const float* __restrict__ fe,
    const int* __restrict__ gt, float* __restrict__ Bsb, float* __restrict__ Csb){
  int g = blockIdx.x*256 + threadIdx.x;
  const float* dr = dbl + (size_t)g*56;
  int id = idx[g];
  int gather = gt[0];
  #pragma unroll
  for (int n = 0; n < NS; ++n){
    Bsb[(size_t)g*NS + n] = dr[24+n];
    float c = dr[40+n];
    if (gather != 0) c += fe[id*NS + n];
    Csb[(size_t)g*NS + n] = c;
  }
}

// scan phase 1: per (b,chunk,d): Aprod[n] = prod a, Boff[n] = local scan end (h0=0)
__global__ __launch_bounds__(384) void k_scan1(const float* __restrict__ delta,
    const float* __restrict__ us, const float* __restrict__ Bsb,
    const float* __restrict__ A_logs, float* __restrict__ Aprod, float* __restrict__ Boff){
  int bc = blockIdx.x;
  int c = bc & (NCHUNKS-1);
  int b = bc >> 5;
  int d = threadIdx.x;
  __shared__ float Bsh[CHUNKLEN*NS];
  int base = b*NL + c*CHUNKLEN;
  for (int p = d; p < CHUNKLEN*NS; p += 384) Bsh[p] = Bsb[(size_t)base*NS + p];
  float An[NS];
  #pragma unroll
  for (int n = 0; n < NS; ++n) An[n] = -expf(A_logs[d*NS + n]);
  float h[NS], ap[NS];
  #pragma unroll
  for (int n = 0; n < NS; ++n){ h[n]=0.f; ap[n]=1.f; }
  __syncthreads();
  for (int s = 0; s < CHUNKLEN; ++s){
    size_t gi = (size_t)(base + s)*NH + d;
    float dlt = delta[gi];
    float uv = us[gi];
    float du = dlt*uv;
    #pragma unroll
    for (int n = 0; n < NS; ++n){
      float a = __expf(dlt*An[n]);
      ap[n] *= a;
      h[n] = a*h[n] + du*Bsh[s*NS+n];
    }
  }
  size_t o = ((size_t)bc*NH + d)*NS;
  #pragma unroll
  for (int n = 0; n < NS; ++n){ Aprod[o+n]=ap[n]; Boff[o+n]=h[n]; }
}

// scan phase 2: compose chunk summaries sequentially -> per-chunk initial state
__global__ __launch_bounds__(256) void k_scan2(const float* __restrict__ Aprod,
    const float* __restrict__ Boff, float* __restrict__ hinit){
  int i = blockIdx.x*256 + threadIdx.x;
  int dn = i % (NH*NS);
  int b = i / (NH*NS);
  float h = 0.f;
  for (int c = 0; c < NCHUNKS; ++c){
    size_t o = ((size_t)(b*NCHUNKS + c)*NH*NS) + dn;
    hinit[o] = h;
    h = Aprod[o]*h + Boff[o];
  }
}

// scan phase 3: re-run local scans with true init; y written in-place over us
__global__ __launch_bounds__(384) void k_scan3(const float* __restrict__ delta,
    const float* __restrict__ Bsb, const float* __restrict__ Csb,
    const float* __restrict__ A_logs, const float* __restrict__ Ds,
    const float* __restrict__ hinit, float* __restrict__ us){
  int bc = blockIdx.x;
  int c = bc & (NCHUNKS-1);
  int b = bc >> 5;
  int d = threadIdx.x;
  __shared__ float Bsh[CHUNKLEN*NS];
  __shared__ float Csh[CHUNKLEN*NS];
  int base = b*NL + c*CHUNKLEN;
  for (int p = d; p < CHUNKLEN*NS; p += 384){
    Bsh[p] = Bsb[(size_t)base*NS + p];
    Csh[p] = Csb[(size_t)base*NS + p];
  }
  float An[NS];
  #pragma unroll
  for (int n = 0; n < NS; ++n) An[n] = -expf(A_logs[d*NS + n]);
  float h[NS];
  size_t ho = ((size_t)bc*NH + d)*NS;
  #pragma unroll
  for (int n = 0; n < NS; ++n) h[n] = hinit[ho + n];
  float Dd = Ds[d];
  __syncthreads();
  for (int s = 0; s < CHUNKLEN; ++s){
    size_t gi = (size_t)(base + s)*NH + d;
    float dlt = delta[gi];
    float uv = us[gi];
    float du = dlt*uv;
    float y = 0.f;
    #pragma unroll
    for (int n = 0; n < NS; ++n){
      float a = __expf(dlt*An[n]);
      h[n] = a*h[n] + du*Bsh[s*NS+n];
      y += h[n]*Csh[s*NS+n];
    }
    us[gi] = y + uv*Dd;
  }
}

// layernorm over hidden (384), in-place; one wave per token
__global__ __launch_bounds__(256) void k_ln(float* __restrict__ y,
    const float* __restrict__ gw, const float* __restrict__ gb){
  int g = blockIdx.x*4 + (threadIdx.x >> 6);
  int lane = threadIdx.x & 63;
  size_t ro = (size_t)g*NH;
  float v[6];
  #pragma unroll
  for (int i = 0; i < 6; ++i) v[i] = y[ro + i*64 + lane];
  float s = 0.f;
  #pragma unroll
  for (int i = 0; i < 6; ++i) s += v[i];
  #pragma unroll
  for (int off = 32; off > 0; off >>= 1) s += __shfl_xor(s, off);
  float mean = s * (1.f/NH);
  float vs = 0.f;
  #pragma unroll
  for (int i = 0; i < 6; ++i){ float d = v[i]-mean; vs += d*d; }
  #pragma unroll
  for (int off = 32; off > 0; off >>= 1) vs += __shfl_xor(vs, off);
  float rstd = rsqrtf(vs*(1.f/NH) + 1e-5f);
  #pragma unroll
  for (int i = 0; i < 6; ++i){
    int col = i*64 + lane;
    y[ro+col] = (v[i]-mean)*rstd*gw[col] + gb[col];
  }
}

extern "C" void kernel_launch(void* const* d_in, const int* in_sizes, int n_in,
                              void* d_out, int out_size, void* d_ws, size_t ws_size,
                              hipStream_t stream){
  const float* x      = (const float*)d_in[0];
  const float* tw     = (const float*)d_in[1];
  const float* gumbel = (const float*)d_in[2];
  const float* embB   = (const float*)d_in[3];
  const float* rw1    = (const float*)d_in[4];
  const float* rb1    = (const float*)d_in[5];
  const float* rw2    = (const float*)d_in[6];
  const float* rb2    = (const float*)d_in[7];
  const float* inw    = (const float*)d_in[8];
  const float* inb    = (const float*)d_in[9];
  const float* cw     = (const float*)d_in[10];
  const float* cb     = (const float*)d_in[11];
  const float* xpw    = (const float*)d_in[12];
  const float* dtw    = (const float*)d_in[13];
  const float* dtb    = (const float*)d_in[14];
  const float* A_logs = (const float*)d_in[15];
  const float* Ds     = (const float*)d_in[16];
  const float* ng     = (const float*)d_in[17];
  const float* nbv    = (const float*)d_in[18];
  const float* ow     = (const float*)d_in[19];
  const float* ob     = (const float*)d_in[20];
  const int*   gt     = (const int*)d_in[23];
  float* out = (float*)d_out;

  float* ws = (float*)d_ws;
  size_t o = 0;
  float* fe   = ws + o; o += 512;
  int* idx    = (int*)(ws + o); o += NTOK;
  int* rmap   = (int*)(ws + o); o += NTOK;
  int* inv    = (int*)(ws + o); o += NTOK;
  float* hmid = ws + o; o += (size_t)NTOK*64;   // reused as dbl (NTOK*56)
  float* xi   = ws + o; o += (size_t)NTOK*NH;   // reused as delta
  float* us   = ws + o; o += (size_t)NTOK*NH;   // reused as y / yn (in-place)
  float* Bsb  = ws + o; o += (size_t)NTOK*NS;
  float* Csb  = ws + o; o += (size_t)NTOK*NS;
  float* Apr  = ws + o; o += (size_t)NB*NCHUNKS*NH*NS;
  float* Bof  = ws + o; o += (size_t)NB*NCHUNKS*NH*NS;
  float* hin  = ws + o; o += (size_t)NB*NCHUNKS*NH*NS;
  float* dbl = hmid;
  float* delta = xi;

  k_emb<<<1,256,0,stream>>>(embB, tw, fe);
  // routing MLP layer 1: hmid = gelu(x @ rw1^T + rb1), 65536x64
  k_gemm<1><<<dim3(NTOK/64,1),256,0,stream>>>(x, ND, rw1, ND, rb1, hmid, 64, 64, ND, nullptr);
  k_argmax<<<NTOK/256,256,0,stream>>>(hmid, rw2, rb2, gumbel, idx);
  k_sort<<<NB,256,0,stream>>>(idx, rmap, inv);
  // in_proj: xi = x @ inw^T + inb, 65536x384
  k_gemm<0><<<dim3(NTOK/64,6),256,0,stream>>>(x, ND, inw, ND, inb, xi, NH, NH, ND, nullptr);
  // CPE gate + scatter to sorted order
  k_cpe<<<NB*64*4,256,0,stream>>>(xi, cw, cb, inv, us);
  // x_dbl = us @ xpw^T, 65536x56
  k_gemm<0><<<dim3(NTOK/64,1),256,0,stream>>>(us, NH, xpw, NH, nullptr, dbl, 56, 56, NH, nullptr);
  k_bc<<<NTOK/256,256,0,stream>>>(dbl, idx, fe, gt, Bsb, Csb);
  // delta = softplus(dbl[:, :24] @ dtw^T + dtb), 65536x384 (overwrites xi)
  k_gemm<2><<<dim3(NTOK/64,6),256,0,stream>>>(dbl, 56, dtw, NR, dtb, delta, NH, NH, NR, nullptr);
  k_scan1<<<NB*NCHUNKS,384,0,stream>>>(delta, us, Bsb, A_logs, Apr, Bof);
  k_scan2<<<(NB*NH*NS)/256,256,0,stream>>>(Apr, Bof, hin);
  k_scan3<<<NB*NCHUNKS,384,0,stream>>>(delta, Bsb, Csb, A_logs, Ds, hin, us);
  k_ln<<<NTOK/4,256,0,stream>>>(us, ng, nbv);
  // out_proj + scatter back to original token order
  k_gemm<3><<<dim3(NTOK/64,3),256,0,stream>>>(us, NH, ow, NH, ob, out, ND, ND, NH, rmap);
}

// Round 3
// 841.577 us; speedup vs baseline: 1.2701x; 1.2701x over previous
//
#include <hip/hip_runtime.h>
#include <math.h>

#define NB 16
#define NL 4096
#define ND 192
#define NH 384
#define NS 16
#define NTK 17
#define NIR 128
#define NR 24
#define NHH 64
#define NWW 64
#define NCHUNKS 32
#define CHUNKLEN 128
#define NTOK (NB*NL)

typedef __attribute__((ext_vector_type(8))) short short8;
typedef __attribute__((ext_vector_type(4))) float floatx4;

__device__ __forceinline__ float gelu_tanh(float x){
  return 0.5f*x*(1.0f + tanhf(0.7978845608028654f*(x + 0.044715f*x*x*x)));
}
__device__ __forceinline__ float softplus_f(float x){
  return (x > 20.0f) ? x : log1pf(expf(x));
}
__device__ __forceinline__ short f2bf(float f){
  unsigned u = __float_as_uint(f);
  unsigned r = (u + 0x7fffu + ((u >> 16) & 1u)) >> 16;
  return (short)r;
}

union Pack8 { uint4 v; short s[8]; };

// full_emb = embB(17x128) @ token_weight(128x16)
__global__ void k_emb(const float* __restrict__ embB, const float* __restrict__ tw,
                      float* __restrict__ fe){
  for (int o = threadIdx.x; o < NTK*NS; o += 256){
    int t = o / NS, s = o % NS;
    float acc = 0.f;
    for (int i = 0; i < NIR; ++i) acc += embB[t*NIR+i]*tw[i*NS+s];
    fe[o] = acc;
  }
}

// convert weights to bf16 (dtw zero-padded K 24->32)
__global__ void k_cvtw(const float* __restrict__ inw, const float* __restrict__ ow,
                       const float* __restrict__ xpw, const float* __restrict__ dtw,
                       short* __restrict__ inwb, short* __restrict__ owb,
                       short* __restrict__ xpwb, short* __restrict__ dtwb){
  int i = blockIdx.x*256 + threadIdx.x;
  int stride = gridDim.x*256;
  for (int p = i; p < NH*ND; p += stride) inwb[p] = f2bf(inw[p]);
  for (int p = i; p < ND*NH; p += stride) owb[p] = f2bf(ow[p]);
  for (int p = i; p < 56*NH; p += stride) xpwb[p] = f2bf(xpw[p]);
  for (int p = i; p < NH*32; p += stride){
    int r = p >> 5, c = p & 31;
    dtwb[p] = (c < NR) ? f2bf(dtw[r*NR + c]) : (short)0;
  }
}

// fp32 GEMM (routing layer only: argmax sensitivity forbids bf16 here)
template<int EPI>
__global__ __launch_bounds__(256) void k_gemm(const float* __restrict__ A, int lda,
    const float* __restrict__ W, int ldw, const float* __restrict__ bias,
    float* __restrict__ C, int ldc, int N, int K){
  __shared__ float As[16][68];
  __shared__ float Ws[16][68];
  int tid = threadIdx.x;
  int m0 = blockIdx.x*64, n0 = blockIdx.y*64;
  int tx = tid & 15, ty = tid >> 4;
  int srow = tid >> 2, skseg = (tid & 3)*4;
  float acc[4][4] = {};
  for (int k0 = 0; k0 < K; k0 += 16){
    {
      const float* ap = A + (size_t)(m0+srow)*lda + k0 + skseg;
      float4 v = *(const float4*)ap;
      As[skseg+0][srow]=v.x; As[skseg+1][srow]=v.y;
      As[skseg+2][srow]=v.z; As[skseg+3][srow]=v.w;
    }
    {
      float4 v = {0.f,0.f,0.f,0.f};
      if (n0 + srow < N) v = *(const float4*)(W + (size_t)(n0+srow)*ldw + k0 + skseg);
      Ws[skseg+0][srow]=v.x; Ws[skseg+1][srow]=v.y;
      Ws[skseg+2][srow]=v.z; Ws[skseg+3][srow]=v.w;
    }
    __syncthreads();
    #pragma unroll
    for (int kk = 0; kk < 16; ++kk){
      float4 av = *(const float4*)&As[kk][ty*4];
      float4 wv = *(const float4*)&Ws[kk][tx*4];
      acc[0][0] += av.x*wv.x; acc[0][1] += av.x*wv.y;
      acc[0][2] += av.x*wv.z; acc[0][3] += av.x*wv.w;
      acc[1][0] += av.y*wv.x; acc[1][1] += av.y*wv.y;
      acc[1][2] += av.y*wv.z; acc[1][3] += av.y*wv.w;
      acc[2][0] += av.z*wv.x; acc[2][1] += av.z*wv.y;
      acc[2][2] += av.z*wv.z; acc[2][3] += av.z*wv.w;
      acc[3][0] += av.w*wv.x; acc[3][1] += av.w*wv.y;
      acc[3][2] += av.w*wv.z; acc[3][3] += av.w*wv.w;
    }
    __syncthreads();
  }
  #pragma unroll
  for (int i = 0; i < 4; ++i){
    int m = m0 + ty*4 + i;
    #pragma unroll
    for (int j = 0; j < 4; ++j){
      int n = n0 + tx*4 + j;
      if (n < N){
        float v = acc[i][j] + (bias ? bias[n] : 0.f);
        if (EPI==1) v = gelu_tanh(v);
        C[(size_t)m*ldc + n] = v;
      }
    }
  }
}

// bf16 MFMA GEMM: C(MxN) = A(MxK) @ W(NxK bf16)^T + bias.
// A is fp32 (AF32=1, converted to bf16 during LDS staging) or bf16 (AF32=0).
// tile 128x64, 4 waves, each wave 32 rows (2 m-tiles) x 4 n-tiles, 16x16x32 mfma.
// EPI: 0 none, 2 softplus, 3 row-scatter via remap
template<int EPI, int AF32>
__global__ __launch_bounds__(256) void k_mfma(const void* __restrict__ Aptr, int lda,
    const short* __restrict__ Wbf, int ldw, const float* __restrict__ bias,
    float* __restrict__ C, int ldc, int N, int K, const int* __restrict__ remap){
  __shared__ short As[128*40];   // stride 40 shorts = 80B: 16B-aligned b128, 2-way banks (free)
  __shared__ short Bs[64*40];
  int tid = threadIdx.x;
  int m0 = blockIdx.x*128, n0 = blockIdx.y*64;
  int w = tid >> 6, lane = tid & 63;
  int lq = lane >> 4, lr = lane & 15;
  floatx4 acc[2][4];
  #pragma unroll
  for (int i = 0; i < 2; ++i)
    #pragma unroll
    for (int j = 0; j < 4; ++j) acc[i][j] = (floatx4){0.f,0.f,0.f,0.f};
  int ar = tid >> 1, aq = (tid & 1)*2;   // A: each thread stages 16 elts of one row
  int br = tid >> 2, bq = tid & 3;       // B: each thread stages 8 elts of one row
  for (int k0 = 0; k0 < K; k0 += 32){
    Pack8 sa0, sa1;
    if (AF32){
      const float* ap = (const float*)Aptr + (size_t)(m0+ar)*lda + k0 + aq*8;
      float4 f0 = *(const float4*)(ap);
      float4 f1 = *(const float4*)(ap+4);
      float4 f2 = *(const float4*)(ap+8);
      float4 f3 = *(const float4*)(ap+12);
      sa0.s[0]=f2bf(f0.x); sa0.s[1]=f2bf(f0.y); sa0.s[2]=f2bf(f0.z); sa0.s[3]=f2bf(f0.w);
      sa0.s[4]=f2bf(f1.x); sa0.s[5]=f2bf(f1.y); sa0.s[6]=f2bf(f1.z); sa0.s[7]=f2bf(f1.w);
      sa1.s[0]=f2bf(f2.x); sa1.s[1]=f2bf(f2.y); sa1.s[2]=f2bf(f2.z); sa1.s[3]=f2bf(f2.w);
      sa1.s[4]=f2bf(f3.x); sa1.s[5]=f2bf(f3.y); sa1.s[6]=f2bf(f3.z); sa1.s[7]=f2bf(f3.w);
    } else {
      const short* ap = (const short*)Aptr + (size_t)(m0+ar)*lda + k0 + aq*8;
      sa0.v = *(const uint4*)ap;
      sa1.v = *(const uint4*)(ap + 8);
    }
    uint4 bv = {0u,0u,0u,0u};
    if (n0 + br < N) bv = *(const uint4*)(Wbf + (size_t)(n0+br)*ldw + k0 + bq*8);
    __syncthreads();
    *(uint4*)&As[ar*40 + aq*8]     = sa0.v;
    *(uint4*)&As[ar*40 + aq*8 + 8] = sa1.v;
    *(uint4*)&Bs[br*40 + bq*8]     = bv;
    __syncthreads();
    short8 a0 = *(const short8*)&As[(w*32      + lr)*40 + lq*8];
    short8 a1 = *(const short8*)&As[(w*32 + 16 + lr)*40 + lq*8];
    short8 b0 = *(const short8*)&Bs[(     lr)*40 + lq*8];
    short8 b1 = *(const short8*)&Bs[(16 + lr)*40 + lq*8];
    short8 b2 = *(const short8*)&Bs[(32 + lr)*40 + lq*8];
    short8 b3 = *(const short8*)&Bs[(48 + lr)*40 + lq*8];
    acc[0][0] = __builtin_amdgcn_mfma_f32_16x16x32_bf16(a0, b0, acc[0][0], 0,0,0);
    acc[0][1] = __builtin_amdgcn_mfma_f32_16x16x32_bf16(a0, b1, acc[0][1], 0,0,0);
    acc[0][2] = __builtin_amdgcn_mfma_f32_16x16x32_bf16(a0, b2, acc[0][2], 0,0,0);
    acc[0][3] = __builtin_amdgcn_mfma_f32_16x16x32_bf16(a0, b3, acc[0][3], 0,0,0);
    acc[1][0] = __builtin_amdgcn_mfma_f32_16x16x32_bf16(a1, b0, acc[1][0], 0,0,0);
    acc[1][1] = __builtin_amdgcn_mfma_f32_16x16x32_bf16(a1, b1, acc[1][1], 0,0,0);
    acc[1][2] = __builtin_amdgcn_mfma_f32_16x16x32_bf16(a1, b2, acc[1][2], 0,0,0);
    acc[1][3] = __builtin_amdgcn_mfma_f32_16x16x32_bf16(a1, b3, acc[1][3], 0,0,0);
  }
  // C/D layout (verified m89): col = lane&15, row = (lane>>4)*4 + reg
  #pragma unroll
  for (int mt = 0; mt < 2; ++mt){
    #pragma unroll
    for (int r = 0; r < 4; ++r){
      int m = m0 + w*32 + mt*16 + lq*4 + r;
      int orow = (EPI==3) ? remap[m] : m;
      #pragma unroll
      for (int nt = 0; nt < 4; ++nt){
        int n = n0 + nt*16 + lr;
        if (n < N){
          float v = acc[mt][nt][r] + (bias ? bias[n] : 0.f);
          if (EPI==2) v = softplus_f(v);
          C[(size_t)orow*ldc + n] = v;
        }
      }
    }
  }
}

// logits = hmid @ w2^T + b2 + gumbel ; idx = argmax (first occurrence)
__global__ __launch_bounds__(256) void k_argmax(const float* __restrict__ hmid,
    const float* __restrict__ w2, const float* __restrict__ b2,
    const float* __restrict__ gumbel, int* __restrict__ idx){
  int g = blockIdx.x*256 + threadIdx.x;
  float hm[64];
  const float4* hp = (const float4*)(hmid + (size_t)g*64);
  #pragma unroll
  for (int i = 0; i < 16; ++i){
    float4 v = hp[i];
    hm[i*4+0]=v.x; hm[i*4+1]=v.y; hm[i*4+2]=v.z; hm[i*4+3]=v.w;
  }
  float best = -INFINITY; int bi = 0;
  for (int c = 0; c < NTK; ++c){
    float s = b2[c] + gumbel[(size_t)g*NTK + c];
    #pragma unroll
    for (int j = 0; j < 64; ++j) s += hm[j]*w2[c*64+j];
    if (s > best){ best = s; bi = c; }
  }
  idx[g] = bi;
}

// stable counting sort per batch over 17 keys
__global__ __launch_bounds__(256) void k_sort(const int* __restrict__ idx,
    int* __restrict__ rmap, int* __restrict__ inv){
  int b = blockIdx.x, t = threadIdx.x;
  __shared__ int hist[NTK][256];
  __shared__ int tot[NTK];
  __shared__ int keybase[NTK];
  int keys[16];
  const int* ip = idx + b*NL + t*16;
  #pragma unroll
  for (int i = 0; i < 16; ++i) keys[i] = ip[i];
  #pragma unroll
  for (int k = 0; k < NTK; ++k){
    int c = 0;
    #pragma unroll
    for (int i = 0; i < 16; ++i) c += (keys[i]==k) ? 1 : 0;
    hist[k][t] = c;
  }
  __syncthreads();
  if (t < NTK){
    int run = 0;
    for (int j = 0; j < 256; ++j){ int v = hist[t][j]; hist[t][j] = run; run += v; }
    tot[t] = run;
  }
  __syncthreads();
  if (t == 0){
    int base = 0;
    for (int k = 0; k < NTK; ++k){ keybase[k] = base; base += tot[k]; }
  }
  __syncthreads();
  #pragma unroll
  for (int i = 0; i < 16; ++i){
    int k = keys[i];
    int cb = 0;
    #pragma unroll
    for (int j = 0; j < 16; ++j) cb += (j < i && keys[j]==k) ? 1 : 0;
    int pos = keybase[k] + hist[k][t] + cb;
    rmap[b*NL + pos] = b*NL + t*16 + i;
    inv[b*NL + t*16 + i] = pos;
  }
}

// depthwise 3x3 SAME conv + sigmoid gate; scatter rows to sorted order
__global__ __launch_bounds__(256) void k_cpe(const float* __restrict__ xi,
    const float* __restrict__ cw, const float* __restrict__ cb,
    const int* __restrict__ inv, float* __restrict__ us){
  int bl = blockIdx.x;
  int cg = bl & 3;
  int xt = (bl>>2) & 7;
  int yt = (bl>>5) & 7;
  int b  = bl >> 8;
  __shared__ float tile[10*10*96];
  int c0 = cg*96;
  for (int p = threadIdx.x; p < 10*10*96; p += 256){
    int c = p % 96; int xx = (p/96) % 10; int yy = p/960;
    int gy = yt*8 + yy - 1, gx = xt*8 + xx - 1;
    float v = 0.f;
    if (gy >= 0 && gy < NHH && gx >= 0 && gx < NWW)
      v = xi[((size_t)(b*NL + gy*NWW + gx))*NH + c0 + c];
    tile[p] = v;
  }
  __syncthreads();
  for (int p = threadIdx.x; p < 8*8*96; p += 256){
    int c = p % 96; int xx = (p/96) % 8; int yy = p/768;
    int ch = c0 + c;
    float acc = cb[ch];
    #pragma unroll
    for (int dy = 0; dy < 3; ++dy)
      #pragma unroll
      for (int dx = 0; dx < 3; ++dx)
        acc += tile[((yy+dy)*10 + (xx+dx))*96 + c] * cw[ch*9 + dy*3 + dx];
    float center = tile[((yy+1)*10 + (xx+1))*96 + c];
    float gate = 1.f/(1.f + expf(-acc));
    int l = (yt*8+yy)*NWW + xt*8+xx;
    int pos = inv[b*NL + l];
    us[((size_t)(b*NL + pos))*NH + ch] = center*gate;
  }
}

// split x_dbl into Bs, Cs (+prompt), and dts as zero-padded bf16 (K=32)
__global__ __launch_bounds__(256) void k_bc(const float* __restrict__ dbl,
    const int* __restrict__ idx, const float* __restrict__ fe,
    const int* __restrict__ gt, float* __restrict__ Bsb, float* __restrict__ Csb,
    short* __restrict__ dtsb){
  int g = blockIdx.x*256 + threadIdx.x;
  const float* dr = dbl + (size_t)g*56;
  int id = idx[g];
  int gather = gt[0];
  #pragma unroll
  for (int n = 0; n < NR; ++n) dtsb[(size_t)g*32 + n] = f2bf(dr[n]);
  #pragma unroll
  for (int n = NR; n < 32; ++n) dtsb[(size_t)g*32 + n] = 0;
  #pragma unroll
  for (int n = 0; n < NS; ++n){
    Bsb[(size_t)g*NS + n] = dr[24+n];
    float c = dr[40+n];
    if (gather != 0) c += fe[id*NS + n];
    Csb[(size_t)g*NS + n] = c;
  }
}

// scan phase 1
__global__ __launch_bounds__(384) void k_scan1(const float* __restrict__ delta,
    const float* __restrict__ us, const float* __restrict__ Bsb,
    const float* __restrict__ A_logs, float* __restrict__ Aprod, float* __restrict__ Boff){
  int bc = blockIdx.x;
  int c = bc & (NCHUNKS-1);
  int b = bc >> 5;
  int d = threadIdx.x;
  __shared__ float Bsh[CHUNKLEN*NS];
  int base = b*NL + c*CHUNKLEN;
  for (int p = d; p < CHUNKLEN*NS; p += 384) Bsh[p] = Bsb[(size_t)base*NS + p];
  float An[NS];
  #pragma unroll
  for (int n = 0; n < NS; ++n) An[n] = -expf(A_logs[d*NS + n]);
  float h[NS], ap[NS];
  #pragma unroll
  for (int n = 0; n < NS; ++n){ h[n]=0.f; ap[n]=1.f; }
  __syncthreads();
  for (int s = 0; s < CHUNKLEN; ++s){
    size_t gi = (size_t)(base + s)*NH + d;
    float dlt = delta[gi];
    float uv = us[gi];
    float du = dlt*uv;
    #pragma unroll
    for (int n = 0; n < NS; ++n){
      float a = __expf(dlt*An[n]);
      ap[n] *= a;
      h[n] = a*h[n] + du*Bsh[s*NS+n];
    }
  }
  size_t o = ((size_t)bc*NH + d)*NS;
  #pragma unroll
  for (int n = 0; n < NS; ++n){ Aprod[o+n]=ap[n]; Boff[o+n]=h[n]; }
}

// scan phase 2: compose chunk summaries; hinit written IN PLACE into Boff
__global__ __launch_bounds__(256) void k_scan2(const float* __restrict__ Aprod,
    float* __restrict__ Boff){
  int i = blockIdx.x*256 + threadIdx.x;
  int dn = i % (NH*NS);
  int b = i / (NH*NS);
  float h = 0.f;
  for (int c = 0; c < NCHUNKS; ++c){
    size_t o = ((size_t)(b*NCHUNKS + c)*NH*NS) + dn;
    float a = Aprod[o];
    float bo = Boff[o];
    Boff[o] = h;
    h = a*h + bo;
  }
}

// scan phase 3 (hinit = Boff after k_scan2)
__global__ __launch_bounds__(384) void k_scan3(const float* __restrict__ delta,
    const float* __restrict__ Bsb, const float* __restrict__ Csb,
    const float* __restrict__ A_logs, const float* __restrict__ Ds,
    const float* __restrict__ hinit, float* __restrict__ us){
  int bc = blockIdx.x;
  int c = bc & (NCHUNKS-1);
  int b = bc >> 5;
  int d = threadIdx.x;
  __shared__ float Bsh[CHUNKLEN*NS];
  __shared__ float Csh[CHUNKLEN*NS];
  int base = b*NL + c*CHUNKLEN;
  for (int p = d; p < CHUNKLEN*NS; p += 384){
    Bsh[p] = Bsb[(size_t)base*NS + p];
    Csh[p] = Csb[(size_t)base*NS + p];
  }
  float An[NS];
  #pragma unroll
  for (int n = 0; n < NS; ++n) An[n] = -expf(A_logs[d*NS + n]);
  float h[NS];
  size_t ho = ((size_t)bc*NH + d)*NS;
  #pragma unroll
  for (int n = 0; n < NS; ++n) h[n] = hinit[ho + n];
  float Dd = Ds[d];
  __syncthreads();
  for (int s = 0; s < CHUNKLEN; ++s){
    size_t gi = (size_t)(base + s)*NH + d;
    float dlt = delta[gi];
    float uv = us[gi];
    float du = dlt*uv;
    float y = 0.f;
    #pragma unroll
    for (int n = 0; n < NS; ++n){
      float a = __expf(dlt*An[n]);
      h[n] = a*h[n] + du*Bsh[s*NS+n];
      y += h[n]*Csh[s*NS+n];
    }
    us[gi] = y + uv*Dd;
  }
}

// layernorm over hidden (384), in-place fp32; one wave per token
__global__ __launch_bounds__(256) void k_ln(float* __restrict__ y,
    const float* __restrict__ gw, const float* __restrict__ gb){
  int g = blockIdx.x*4 + (threadIdx.x >> 6);
  int lane = threadIdx.x & 63;
  size_t ro = (size_t)g*NH;
  float v[6];
  #pragma unroll
  for (int i = 0; i < 6; ++i) v[i] = y[ro + i*64 + lane];
  float s = 0.f;
  #pragma unroll
  for (int i = 0; i < 6; ++i) s += v[i];
  #pragma unroll
  for (int off = 32; off > 0; off >>= 1) s += __shfl_xor(s, off);
  float mean = s * (1.f/NH);
  float vs = 0.f;
  #pragma unroll
  for (int i = 0; i < 6; ++i){ float d = v[i]-mean; vs += d*d; }
  #pragma unroll
  for (int off = 32; off > 0; off >>= 1) vs += __shfl_xor(vs, off);
  float rstd = rsqrtf(vs*(1.f/NH) + 1e-5f);
  #pragma unroll
  for (int i = 0; i < 6; ++i){
    int col = i*64 + lane;
    y[ro+col] = (v[i]-mean)*rstd*gw[col] + gb[col];
  }
}

extern "C" void kernel_launch(void* const* d_in, const int* in_sizes, int n_in,
                              void* d_out, int out_size, void* d_ws, size_t ws_size,
                              hipStream_t stream){
  const float* x      = (const float*)d_in[0];
  const float* tw     = (const float*)d_in[1];
  const float* gumbel = (const float*)d_in[2];
  const float* embB   = (const float*)d_in[3];
  const float* rw1    = (const float*)d_in[4];
  const float* rb1    = (const float*)d_in[5];
  const float* rw2    = (const float*)d_in[6];
  const float* rb2    = (const float*)d_in[7];
  const float* inw    = (const float*)d_in[8];
  const float* inb    = (const float*)d_in[9];
  const float* cw     = (const float*)d_in[10];
  const float* cb     = (const float*)d_in[11];
  const float* xpw    = (const float*)d_in[12];
  const float* dtw    = (const float*)d_in[13];
  const float* dtb    = (const float*)d_in[14];
  const float* A_logs = (const float*)d_in[15];
  const float* Ds     = (const float*)d_in[16];
  const float* ng     = (const float*)d_in[17];
  const float* nbv    = (const float*)d_in[18];
  const float* ow     = (const float*)d_in[19];
  const float* ob     = (const float*)d_in[20];
  const int*   gt     = (const int*)d_in[23];
  float* out = (float*)d_out;

  // Workspace layout — total 63,202,336 floats = 252.8 MB (round-1's 265.0 MB passed)
  float* ws = (float*)d_ws;
  size_t o = 0;
  float* fe   = ws + o; o += 512;
  int* idx    = (int*)(ws + o); o += NTOK;
  int* rmap   = (int*)(ws + o); o += NTOK;
  int* inv    = (int*)(ws + o); o += NTOK;
  float* hmid = ws + o; o += (size_t)NTOK*64;   // reused as dbl (NTOK*56)
  float* xi   = ws + o; o += (size_t)NTOK*NH;   // reused as delta
  float* us   = ws + o; o += (size_t)NTOK*NH;   // u -> y -> yn (in-place)
  float* Bsb  = ws + o; o += (size_t)NTOK*NS;
  float* Csb  = ws + o; o += (size_t)NTOK*NS;
  float* Apr  = ws + o; o += (size_t)NB*NCHUNKS*NH*NS;  // dtsb aliases this (disjoint lifetime)
  float* Bof  = ws + o; o += (size_t)NB*NCHUNKS*NH*NS;  // becomes hinit in-place via k_scan2
  short* inwb = (short*)(ws + o); o += (NH*ND)/2;
  short* owb  = (short*)(ws + o); o += (ND*NH)/2;
  short* xpwb = (short*)(ws + o); o += (56*NH)/2 + 32;
  short* dtwb = (short*)(ws + o); o += (NH*32)/2;
  float* dbl = hmid;
  float* delta = xi;
  short* dtsb = (short*)Apr;   // NTOK*32 shorts = 4 MB, dies before scan1 writes Apr

  k_emb<<<1,256,0,stream>>>(embB, tw, fe);
  k_cvtw<<<64,256,0,stream>>>(inw, ow, xpw, dtw, inwb, owb, xpwb, dtwb);
  // routing MLP layer 1 (fp32: argmax margins too tight for bf16)
  k_gemm<1><<<dim3(NTOK/64,1),256,0,stream>>>(x, ND, rw1, ND, rb1, hmid, 64, 64, ND);
  k_argmax<<<NTOK/256,256,0,stream>>>(hmid, rw2, rb2, gumbel, idx);
  k_sort<<<NB,256,0,stream>>>(idx, rmap, inv);
  // in_proj: xi = x @ inw^T + inb (bf16 MFMA, fp32 A converted in staging)
  k_mfma<0,1><<<dim3(NTOK/128,6),256,0,stream>>>(x, ND, inwb, ND, inb, xi, NH, NH, ND, nullptr);
  // CPE gate + scatter to sorted order
  k_cpe<<<NB*64*4,256,0,stream>>>(xi, cw, cb, inv, us);
  // x_dbl = us @ xpw^T (bf16 MFMA, N=56)
  k_mfma<0,1><<<dim3(NTOK/128,1),256,0,stream>>>(us, NH, xpwb, NH, nullptr, dbl, 56, 56, NH, nullptr);
  k_bc<<<NTOK/256,256,0,stream>>>(dbl, idx, fe, gt, Bsb, Csb, dtsb);
  // delta = softplus(dts @ dtw^T + dtb)  (bf16 MFMA, K=32 padded)
  k_mfma<2,0><<<dim3(NTOK/128,6),256,0,stream>>>(dtsb, 32, dtwb, 32, dtb, delta, NH, NH, 32, nullptr);
  k_scan1<<<NB*NCHUNKS,384,0,stream>>>(delta, us, Bsb, A_logs, Apr, Bof);
  k_scan2<<<(NB*NH*NS)/256,256,0,stream>>>(Apr, Bof);
  k_scan3<<<NB*NCHUNKS,384,0,stream>>>(delta, Bsb, Csb, A_logs, Ds, Bof, us);
  k_ln<<<NTOK/4,256,0,stream>>>(us, ng, nbv);
  // out_proj + scatter back to original token order (bf16 MFMA, fp32 A)
  k_mfma<3,1><<<dim3(NTOK/128,3),256,0,stream>>>(us, NH, owb, NH, ob, out, ND, ND, NH, rmap);
}

// Round 5
// 785.096 us; speedup vs baseline: 1.3615x; 1.0719x over previous
//
#include <hip/hip_runtime.h>
#include <math.h>

#define NB 16
#define NL 4096
#define ND 192
#define NH 384
#define NS 16
#define NTK 17
#define NIR 128
#define NR 24
#define NHH 64
#define NWW 64
#define NCHUNKS 32
#define CHUNKLEN 128
#define NTOK (NB*NL)

typedef __attribute__((ext_vector_type(8))) short short8;
typedef __attribute__((ext_vector_type(4))) float floatx4;

__device__ __forceinline__ float gelu_tanh(float x){
  return 0.5f*x*(1.0f + tanhf(0.7978845608028654f*(x + 0.044715f*x*x*x)));
}
__device__ __forceinline__ float softplus_f(float x){
  return (x > 20.0f) ? x : log1pf(expf(x));
}
__device__ __forceinline__ short f2bf(float f){
  unsigned u = __float_as_uint(f);
  unsigned r = (u + 0x7fffu + ((u >> 16) & 1u)) >> 16;
  return (short)r;
}

union Pack8 { uint4 v; short s[8]; };

// full_emb = embB(17x128) @ token_weight(128x16)
__global__ void k_emb(const float* __restrict__ embB, const float* __restrict__ tw,
                      float* __restrict__ fe){
  for (int o = threadIdx.x; o < NTK*NS; o += 256){
    int t = o / NS, s = o % NS;
    float acc = 0.f;
    for (int i = 0; i < NIR; ++i) acc += embB[t*NIR+i]*tw[i*NS+s];
    fe[o] = acc;
  }
}

// convert weights to bf16 (dtw zero-padded K 24->32)
__global__ void k_cvtw(const float* __restrict__ inw, const float* __restrict__ ow,
                       const float* __restrict__ xpw, const float* __restrict__ dtw,
                       short* __restrict__ inwb, short* __restrict__ owb,
                       short* __restrict__ xpwb, short* __restrict__ dtwb){
  int i = blockIdx.x*256 + threadIdx.x;
  int stride = gridDim.x*256;
  for (int p = i; p < NH*ND; p += stride) inwb[p] = f2bf(inw[p]);
  for (int p = i; p < ND*NH; p += stride) owb[p] = f2bf(ow[p]);
  for (int p = i; p < 56*NH; p += stride) xpwb[p] = f2bf(xpw[p]);
  for (int p = i; p < NH*32; p += stride){
    int r = p >> 5, c = p & 31;
    dtwb[p] = (c < NR) ? f2bf(dtw[r*NR + c]) : (short)0;
  }
}

// fp32 GEMM (routing layer only: argmax sensitivity forbids bf16 here)
template<int EPI>
__global__ __launch_bounds__(256) void k_gemm(const float* __restrict__ A, int lda,
    const float* __restrict__ W, int ldw, const float* __restrict__ bias,
    float* __restrict__ C, int ldc, int N, int K){
  __shared__ float As[16][68];
  __shared__ float Ws[16][68];
  int tid = threadIdx.x;
  int m0 = blockIdx.x*64, n0 = blockIdx.y*64;
  int tx = tid & 15, ty = tid >> 4;
  int srow = tid >> 2, skseg = (tid & 3)*4;
  float acc[4][4] = {};
  for (int k0 = 0; k0 < K; k0 += 16){
    {
      const float* ap = A + (size_t)(m0+srow)*lda + k0 + skseg;
      float4 v = *(const float4*)ap;
      As[skseg+0][srow]=v.x; As[skseg+1][srow]=v.y;
      As[skseg+2][srow]=v.z; As[skseg+3][srow]=v.w;
    }
    {
      float4 v = {0.f,0.f,0.f,0.f};
      if (n0 + srow < N) v = *(const float4*)(W + (size_t)(n0+srow)*ldw + k0 + skseg);
      Ws[skseg+0][srow]=v.x; Ws[skseg+1][srow]=v.y;
      Ws[skseg+2][srow]=v.z; Ws[skseg+3][srow]=v.w;
    }
    __syncthreads();
    #pragma unroll
    for (int kk = 0; kk < 16; ++kk){
      float4 av = *(const float4*)&As[kk][ty*4];
      float4 wv = *(const float4*)&Ws[kk][tx*4];
      acc[0][0] += av.x*wv.x; acc[0][1] += av.x*wv.y;
      acc[0][2] += av.x*wv.z; acc[0][3] += av.x*wv.w;
      acc[1][0] += av.y*wv.x; acc[1][1] += av.y*wv.y;
      acc[1][2] += av.y*wv.z; acc[1][3] += av.y*wv.w;
      acc[2][0] += av.z*wv.x; acc[2][1] += av.z*wv.y;
      acc[2][2] += av.z*wv.z; acc[2][3] += av.z*wv.w;
      acc[3][0] += av.w*wv.x; acc[3][1] += av.w*wv.y;
      acc[3][2] += av.w*wv.z; acc[3][3] += av.w*wv.w;
    }
    __syncthreads();
  }
  #pragma unroll
  for (int i = 0; i < 4; ++i){
    int m = m0 + ty*4 + i;
    #pragma unroll
    for (int j = 0; j < 4; ++j){
      int n = n0 + tx*4 + j;
      if (n < N){
        float v = acc[i][j] + (bias ? bias[n] : 0.f);
        if (EPI==1) v = gelu_tanh(v);
        C[(size_t)m*ldc + n] = v;
      }
    }
  }
}

// bf16 MFMA GEMM: C(MxN) = A(MxK) @ W(NxK bf16)^T + bias.
// A is fp32 (AF32=1, converted to bf16 during LDS staging) or bf16 (AF32=0).
// tile 128x64, 4 waves, each wave 32 rows (2 m-tiles) x 4 n-tiles, 16x16x32 mfma.
// EPI: 0 none, 2 softplus, 3 row-scatter via remap
template<int EPI, int AF32>
__global__ __launch_bounds__(256) void k_mfma(const void* __restrict__ Aptr, int lda,
    const short* __restrict__ Wbf, int ldw, const float* __restrict__ bias,
    float* __restrict__ C, int ldc, int N, int K, const int* __restrict__ remap){
  __shared__ short As[128*40];   // stride 40 shorts = 80B: 16B-aligned b128, 2-way banks (free)
  __shared__ short Bs[64*40];
  int tid = threadIdx.x;
  int m0 = blockIdx.x*128, n0 = blockIdx.y*64;
  int w = tid >> 6, lane = tid & 63;
  int lq = lane >> 4, lr = lane & 15;
  floatx4 acc[2][4];
  #pragma unroll
  for (int i = 0; i < 2; ++i)
    #pragma unroll
    for (int j = 0; j < 4; ++j) acc[i][j] = (floatx4){0.f,0.f,0.f,0.f};
  int ar = tid >> 1, aq = (tid & 1)*2;   // A: each thread stages 16 elts of one row
  int br = tid >> 2, bq = tid & 3;       // B: each thread stages 8 elts of one row
  for (int k0 = 0; k0 < K; k0 += 32){
    Pack8 sa0, sa1;
    if (AF32){
      const float* ap = (const float*)Aptr + (size_t)(m0+ar)*lda + k0 + aq*8;
      float4 f0 = *(const float4*)(ap);
      float4 f1 = *(const float4*)(ap+4);
      float4 f2 = *(const float4*)(ap+8);
      float4 f3 = *(const float4*)(ap+12);
      sa0.s[0]=f2bf(f0.x); sa0.s[1]=f2bf(f0.y); sa0.s[2]=f2bf(f0.z); sa0.s[3]=f2bf(f0.w);
      sa0.s[4]=f2bf(f1.x); sa0.s[5]=f2bf(f1.y); sa0.s[6]=f2bf(f1.z); sa0.s[7]=f2bf(f1.w);
      sa1.s[0]=f2bf(f2.x); sa1.s[1]=f2bf(f2.y); sa1.s[2]=f2bf(f2.z); sa1.s[3]=f2bf(f2.w);
      sa1.s[4]=f2bf(f3.x); sa1.s[5]=f2bf(f3.y); sa1.s[6]=f2bf(f3.z); sa1.s[7]=f2bf(f3.w);
    } else {
      const short* ap = (const short*)Aptr + (size_t)(m0+ar)*lda + k0 + aq*8;
      sa0.v = *(const uint4*)ap;
      sa1.v = *(const uint4*)(ap + 8);
    }
    uint4 bv = {0u,0u,0u,0u};
    if (n0 + br < N) bv = *(const uint4*)(Wbf + (size_t)(n0+br)*ldw + k0 + bq*8);
    __syncthreads();
    *(uint4*)&As[ar*40 + aq*8]     = sa0.v;
    *(uint4*)&As[ar*40 + aq*8 + 8] = sa1.v;
    *(uint4*)&Bs[br*40 + bq*8]     = bv;
    __syncthreads();
    short8 a0 = *(const short8*)&As[(w*32      + lr)*40 + lq*8];
    short8 a1 = *(const short8*)&As[(w*32 + 16 + lr)*40 + lq*8];
    short8 b0 = *(const short8*)&Bs[(     lr)*40 + lq*8];
    short8 b1 = *(const short8*)&Bs[(16 + lr)*40 + lq*8];
    short8 b2 = *(const short8*)&Bs[(32 + lr)*40 + lq*8];
    short8 b3 = *(const short8*)&Bs[(48 + lr)*40 + lq*8];
    acc[0][0] = __builtin_amdgcn_mfma_f32_16x16x32_bf16(a0, b0, acc[0][0], 0,0,0);
    acc[0][1] = __builtin_amdgcn_mfma_f32_16x16x32_bf16(a0, b1, acc[0][1], 0,0,0);
    acc[0][2] = __builtin_amdgcn_mfma_f32_16x16x32_bf16(a0, b2, acc[0][2], 0,0,0);
    acc[0][3] = __builtin_amdgcn_mfma_f32_16x16x32_bf16(a0, b3, acc[0][3], 0,0,0);
    acc[1][0] = __builtin_amdgcn_mfma_f32_16x16x32_bf16(a1, b0, acc[1][0], 0,0,0);
    acc[1][1] = __builtin_amdgcn_mfma_f32_16x16x32_bf16(a1, b1, acc[1][1], 0,0,0);
    acc[1][2] = __builtin_amdgcn_mfma_f32_16x16x32_bf16(a1, b2, acc[1][2], 0,0,0);
    acc[1][3] = __builtin_amdgcn_mfma_f32_16x16x32_bf16(a1, b3, acc[1][3], 0,0,0);
  }
  // C/D layout (verified m89): col = lane&15, row = (lane>>4)*4 + reg
  #pragma unroll
  for (int mt = 0; mt < 2; ++mt){
    #pragma unroll
    for (int r = 0; r < 4; ++r){
      int m = m0 + w*32 + mt*16 + lq*4 + r;
      int orow = (EPI==3) ? remap[m] : m;
      #pragma unroll
      for (int nt = 0; nt < 4; ++nt){
        int n = n0 + nt*16 + lr;
        if (n < N){
          float v = acc[mt][nt][r] + (bias ? bias[n] : 0.f);
          if (EPI==2) v = softplus_f(v);
          C[(size_t)orow*ldc + n] = v;
        }
      }
    }
  }
}

// logits = hmid @ w2^T + b2 + gumbel ; idx = argmax (first occurrence)
__global__ __launch_bounds__(256) void k_argmax(const float* __restrict__ hmid,
    const float* __restrict__ w2, const float* __restrict__ b2,
    const float* __restrict__ gumbel, int* __restrict__ idx){
  int g = blockIdx.x*256 + threadIdx.x;
  float hm[64];
  const float4* hp = (const float4*)(hmid + (size_t)g*64);
  #pragma unroll
  for (int i = 0; i < 16; ++i){
    float4 v = hp[i];
    hm[i*4+0]=v.x; hm[i*4+1]=v.y; hm[i*4+2]=v.z; hm[i*4+3]=v.w;
  }
  float best = -INFINITY; int bi = 0;
  for (int c = 0; c < NTK; ++c){
    float s = b2[c] + gumbel[(size_t)g*NTK + c];
    #pragma unroll
    for (int j = 0; j < 64; ++j) s += hm[j]*w2[c*64+j];
    if (s > best){ best = s; bi = c; }
  }
  idx[g] = bi;
}

// stable counting sort per batch over 17 keys
__global__ __launch_bounds__(256) void k_sort(const int* __restrict__ idx,
    int* __restrict__ rmap, int* __restrict__ inv){
  int b = blockIdx.x, t = threadIdx.x;
  __shared__ int hist[NTK][256];
  __shared__ int tot[NTK];
  __shared__ int keybase[NTK];
  int keys[16];
  const int* ip = idx + b*NL + t*16;
  #pragma unroll
  for (int i = 0; i < 16; ++i) keys[i] = ip[i];
  #pragma unroll
  for (int k = 0; k < NTK; ++k){
    int c = 0;
    #pragma unroll
    for (int i = 0; i < 16; ++i) c += (keys[i]==k) ? 1 : 0;
    hist[k][t] = c;
  }
  __syncthreads();
  if (t < NTK){
    int run = 0;
    for (int j = 0; j < 256; ++j){ int v = hist[t][j]; hist[t][j] = run; run += v; }
    tot[t] = run;
  }
  __syncthreads();
  if (t == 0){
    int base = 0;
    for (int k = 0; k < NTK; ++k){ keybase[k] = base; base += tot[k]; }
  }
  __syncthreads();
  #pragma unroll
  for (int i = 0; i < 16; ++i){
    int k = keys[i];
    int cb = 0;
    #pragma unroll
    for (int j = 0; j < 16; ++j) cb += (j < i && keys[j]==k) ? 1 : 0;
    int pos = keybase[k] + hist[k][t] + cb;
    rmap[b*NL + pos] = b*NL + t*16 + i;
    inv[b*NL + t*16 + i] = pos;
  }
}

// depthwise 3x3 SAME conv + sigmoid gate; scatter rows to sorted order
__global__ __launch_bounds__(256) void k_cpe(const float* __restrict__ xi,
    const float* __restrict__ cw, const float* __restrict__ cb,
    const int* __restrict__ inv, float* __restrict__ us){
  int bl = blockIdx.x;
  int cg = bl & 3;
  int xt = (bl>>2) & 7;
  int yt = (bl>>5) & 7;
  int b  = bl >> 8;
  __shared__ float tile[10*10*96];
  int c0 = cg*96;
  for (int p = threadIdx.x; p < 10*10*96; p += 256){
    int c = p % 96; int xx = (p/96) % 10; int yy = p/960;
    int gy = yt*8 + yy - 1, gx = xt*8 + xx - 1;
    float v = 0.f;
    if (gy >= 0 && gy < NHH && gx >= 0 && gx < NWW)
      v = xi[((size_t)(b*NL + gy*NWW + gx))*NH + c0 + c];
    tile[p] = v;
  }
  __syncthreads();
  for (int p = threadIdx.x; p < 8*8*96; p += 256){
    int c = p % 96; int xx = (p/96) % 8; int yy = p/768;
    int ch = c0 + c;
    float acc = cb[ch];
    #pragma unroll
    for (int dy = 0; dy < 3; ++dy)
      #pragma unroll
      for (int dx = 0; dx < 3; ++dx)
        acc += tile[((yy+dy)*10 + (xx+dx))*96 + c] * cw[ch*9 + dy*3 + dx];
    float center = tile[((yy+1)*10 + (xx+1))*96 + c];
    float gate = 1.f/(1.f + expf(-acc));
    int l = (yt*8+yy)*NWW + xt*8+xx;
    int pos = inv[b*NL + l];
    us[((size_t)(b*NL + pos))*NH + ch] = center*gate;
  }
}

// split x_dbl into Bs, Cs (+prompt), and dts as zero-padded bf16 (K=32)
__global__ __launch_bounds__(256) void k_bc(const float* __restrict__ dbl,
    const int* __restrict__ idx, const float* __restrict__ fe,
    const int* __restrict__ gt, float* __restrict__ Bsb, float* __restrict__ Csb,
    short* __restrict__ dtsb){
  int g = blockIdx.x*256 + threadIdx.x;
  const float* dr = dbl + (size_t)g*56;
  int id = idx[g];
  int gather = gt[0];
  #pragma unroll
  for (int n = 0; n < NR; ++n) dtsb[(size_t)g*32 + n] = f2bf(dr[n]);
  #pragma unroll
  for (int n = NR; n < 32; ++n) dtsb[(size_t)g*32 + n] = 0;
  #pragma unroll
  for (int n = 0; n < NS; ++n){
    Bsb[(size_t)g*NS + n] = dr[24+n];
    float c = dr[40+n];
    if (gather != 0) c += fe[id*NS + n];
    Csb[(size_t)g*NS + n] = c;
  }
}

// decay helper: a[n] = exp(dlt*An[n]); if An[n]==(n+1)*An[0] (A_logs structure),
// use 1 exp + 15 muls (powers of r). Fallback: 16 exps (general correctness).
__device__ __forceinline__ void decay16(bool pw, float dlt, const float* An, float* a){
  if (pw){
    float r = __expf(dlt*An[0]);
    a[0] = r;
    #pragma unroll
    for (int n = 1; n < NS; ++n) a[n] = a[n-1]*r;
  } else {
    #pragma unroll
    for (int n = 0; n < NS; ++n) a[n] = __expf(dlt*An[n]);
  }
}
__device__ __forceinline__ bool pwcheck(const float* An){
  bool pw = true;
  #pragma unroll
  for (int n = 1; n < NS; ++n)
    pw = pw && (fabsf(An[n] - (n+1)*An[0]) <= 1e-4f*fabsf(An[n]));
  return pw;
}

// scan phase 1: per (b,chunk,d): Aprod[n] = prod a, Boff[n] = local scan end (h0=0)
__global__ __launch_bounds__(384) void k_scan1(const float* __restrict__ delta,
    const float* __restrict__ us, const float* __restrict__ Bsb,
    const float* __restrict__ A_logs, float* __restrict__ Aprod, float* __restrict__ Boff){
  int bc = blockIdx.x;
  int c = bc & (NCHUNKS-1);
  int b = bc >> 5;
  int d = threadIdx.x;
  __shared__ float Bsh[CHUNKLEN*NS];
  int base = b*NL + c*CHUNKLEN;
  for (int p = d; p < CHUNKLEN*NS; p += 384) Bsh[p] = Bsb[(size_t)base*NS + p];
  float An[NS];
  #pragma unroll
  for (int n = 0; n < NS; ++n) An[n] = -expf(A_logs[d*NS + n]);
  bool pw = pwcheck(An);
  float h[NS], ap[NS];
  #pragma unroll
  for (int n = 0; n < NS; ++n){ h[n]=0.f; ap[n]=1.f; }
  __syncthreads();
  for (int s = 0; s < CHUNKLEN; ++s){
    size_t gi = (size_t)(base + s)*NH + d;
    float dlt = delta[gi];
    float uv = us[gi];
    float du = dlt*uv;
    float a[NS];
    decay16(pw, dlt, An, a);
    #pragma unroll
    for (int n = 0; n < NS; ++n){
      ap[n] *= a[n];
      h[n] = a[n]*h[n] + du*Bsh[s*NS+n];
    }
  }
  size_t o = ((size_t)bc*NH + d)*NS;
  #pragma unroll
  for (int n = 0; n < NS; ++n){ Aprod[o+n]=ap[n]; Boff[o+n]=h[n]; }
}

// scan phase 2: compose chunk summaries; hinit written IN PLACE into Boff
__global__ __launch_bounds__(256) void k_scan2(const float* __restrict__ Aprod,
    float* __restrict__ Boff){
  int i = blockIdx.x*256 + threadIdx.x;
  int dn = i % (NH*NS);
  int b = i / (NH*NS);
  float h = 0.f;
  for (int c = 0; c < NCHUNKS; ++c){
    size_t o = ((size_t)(b*NCHUNKS + c)*NH*NS) + dn;
    float a = Aprod[o];
    float bo = Boff[o];
    Boff[o] = h;
    h = a*h + bo;
  }
}

// scan phase 3 (hinit = Boff after k_scan2)
__global__ __launch_bounds__(384) void k_scan3(const float* __restrict__ delta,
    const float* __restrict__ Bsb, const float* __restrict__ Csb,
    const float* __restrict__ A_logs, const float* __restrict__ Ds,
    const float* __restrict__ hinit, float* __restrict__ us){
  int bc = blockIdx.x;
  int c = bc & (NCHUNKS-1);
  int b = bc >> 5;
  int d = threadIdx.x;
  __shared__ float Bsh[CHUNKLEN*NS];
  __shared__ float Csh[CHUNKLEN*NS];
  int base = b*NL + c*CHUNKLEN;
  for (int p = d; p < CHUNKLEN*NS; p += 384){
    Bsh[p] = Bsb[(size_t)base*NS + p];
    Csh[p] = Csb[(size_t)base*NS + p];
  }
  float An[NS];
  #pragma unroll
  for (int n = 0; n < NS; ++n) An[n] = -expf(A_logs[d*NS + n]);
  bool pw = pwcheck(An);
  float h[NS];
  size_t ho = ((size_t)bc*NH + d)*NS;
  #pragma unroll
  for (int n = 0; n < NS; ++n) h[n] = hinit[ho + n];
  float Dd = Ds[d];
  __syncthreads();
  for (int s = 0; s < CHUNKLEN; ++s){
    size_t gi = (size_t)(base + s)*NH + d;
    float dlt = delta[gi];
    float uv = us[gi];
    float du = dlt*uv;
    float a[NS];
    decay16(pw, dlt, An, a);
    float y = 0.f;
    #pragma unroll
    for (int n = 0; n < NS; ++n){
      h[n] = a[n]*h[n] + du*Bsh[s*NS+n];
      y += h[n]*Csh[s*NS+n];
    }
    us[gi] = y + uv*Dd;
  }
}

// layernorm over hidden (384), in-place fp32; one wave per token
__global__ __launch_bounds__(256) void k_ln(float* __restrict__ y,
    const float* __restrict__ gw, const float* __restrict__ gb){
  int g = blockIdx.x*4 + (threadIdx.x >> 6);
  int lane = threadIdx.x & 63;
  size_t ro = (size_t)g*NH;
  float v[6];
  #pragma unroll
  for (int i = 0; i < 6; ++i) v[i] = y[ro + i*64 + lane];
  float s = 0.f;
  #pragma unroll
  for (int i = 0; i < 6; ++i) s += v[i];
  #pragma unroll
  for (int off = 32; off > 0; off >>= 1) s += __shfl_xor(s, off);
  float mean = s * (1.f/NH);
  float vs = 0.f;
  #pragma unroll
  for (int i = 0; i < 6; ++i){ float d = v[i]-mean; vs += d*d; }
  #pragma unroll
  for (int off = 32; off > 0; off >>= 1) vs += __shfl_xor(vs, off);
  float rstd = rsqrtf(vs*(1.f/NH) + 1e-5f);
  #pragma unroll
  for (int i = 0; i < 6; ++i){
    int col = i*64 + lane;
    y[ro+col] = (v[i]-mean)*rstd*gw[col] + gb[col];
  }
}

extern "C" void kernel_launch(void* const* d_in, const int* in_sizes, int n_in,
                              void* d_out, int out_size, void* d_ws, size_t ws_size,
                              hipStream_t stream){
  const float* x      = (const float*)d_in[0];
  const float* tw     = (const float*)d_in[1];
  const float* gumbel = (const float*)d_in[2];
  const float* embB   = (const float*)d_in[3];
  const float* rw1    = (const float*)d_in[4];
  const float* rb1    = (const float*)d_in[5];
  const float* rw2    = (const float*)d_in[6];
  const float* rb2    = (const float*)d_in[7];
  const float* inw    = (const float*)d_in[8];
  const float* inb    = (const float*)d_in[9];
  const float* cw     = (const float*)d_in[10];
  const float* cb     = (const float*)d_in[11];
  const float* xpw    = (const float*)d_in[12];
  const float* dtw    = (const float*)d_in[13];
  const float* dtb    = (const float*)d_in[14];
  const float* A_logs = (const float*)d_in[15];
  const float* Ds     = (const float*)d_in[16];
  const float* ng     = (const float*)d_in[17];
  const float* nbv    = (const float*)d_in[18];
  const float* ow     = (const float*)d_in[19];
  const float* ob     = (const float*)d_in[20];
  const int*   gt     = (const int*)d_in[23];
  float* out = (float*)d_out;

  // Workspace layout — IDENTICAL to round 3 (known-good through full harness).
  float* ws = (float*)d_ws;
  size_t o = 0;
  float* fe   = ws + o; o += 512;
  int* idx    = (int*)(ws + o); o += NTOK;
  int* rmap   = (int*)(ws + o); o += NTOK;
  int* inv    = (int*)(ws + o); o += NTOK;
  float* hmid = ws + o; o += (size_t)NTOK*64;   // reused as dbl (NTOK*56)
  float* xi   = ws + o; o += (size_t)NTOK*NH;   // reused as delta
  float* us   = ws + o; o += (size_t)NTOK*NH;   // u -> y -> yn (in-place)
  float* Bsb  = ws + o; o += (size_t)NTOK*NS;
  float* Csb  = ws + o; o += (size_t)NTOK*NS;
  float* Apr  = ws + o; o += (size_t)NB*NCHUNKS*NH*NS;  // dtsb aliases this (disjoint lifetime)
  float* Bof  = ws + o; o += (size_t)NB*NCHUNKS*NH*NS;  // becomes hinit in-place via k_scan2
  short* inwb = (short*)(ws + o); o += (NH*ND)/2;
  short* owb  = (short*)(ws + o); o += (ND*NH)/2;
  short* xpwb = (short*)(ws + o); o += (56*NH)/2 + 32;
  short* dtwb = (short*)(ws + o); o += (NH*32)/2;
  float* dbl = hmid;
  float* delta = xi;
  short* dtsb = (short*)Apr;   // NTOK*32 shorts = 4 MB, dies before scan1 writes Apr

  k_emb<<<1,256,0,stream>>>(embB, tw, fe);
  k_cvtw<<<64,256,0,stream>>>(inw, ow, xpw, dtw, inwb, owb, xpwb, dtwb);
  // routing MLP layer 1 (fp32: argmax margins too tight for bf16)
  k_gemm<1><<<dim3(NTOK/64,1),256,0,stream>>>(x, ND, rw1, ND, rb1, hmid, 64, 64, ND);
  k_argmax<<<NTOK/256,256,0,stream>>>(hmid, rw2, rb2, gumbel, idx);
  k_sort<<<NB,256,0,stream>>>(idx, rmap, inv);
  // in_proj: xi = x @ inw^T + inb (bf16 MFMA, fp32 A converted in staging)
  k_mfma<0,1><<<dim3(NTOK/128,6),256,0,stream>>>(x, ND, inwb, ND, inb, xi, NH, NH, ND, nullptr);
  // CPE gate + scatter to sorted order
  k_cpe<<<NB*64*4,256,0,stream>>>(xi, cw, cb, inv, us);
  // x_dbl = us @ xpw^T (bf16 MFMA, N=56)
  k_mfma<0,1><<<dim3(NTOK/128,1),256,0,stream>>>(us, NH, xpwb, NH, nullptr, dbl, 56, 56, NH, nullptr);
  k_bc<<<NTOK/256,256,0,stream>>>(dbl, idx, fe, gt, Bsb, Csb, dtsb);
  // delta = softplus(dts @ dtw^T + dtb)  (bf16 MFMA, K=32 padded)
  k_mfma<2,0><<<dim3(NTOK/128,6),256,0,stream>>>(dtsb, 32, dtwb, 32, dtb, delta, NH, NH, 32, nullptr);
  k_scan1<<<NB*NCHUNKS,384,0,stream>>>(delta, us, Bsb, A_logs, Apr, Bof);
  k_scan2<<<(NB*NH*NS)/256,256,0,stream>>>(Apr, Bof);
  k_scan3<<<NB*NCHUNKS,384,0,stream>>>(delta, Bsb, Csb, A_logs, Ds, Bof, us);
  k_ln<<<NTOK/4,256,0,stream>>>(us, ng, nbv);
  // out_proj + scatter back to original token order (bf16 MFMA, fp32 A)
  k_mfma<3,1><<<dim3(NTOK/128,3),256,0,stream>>>(us, NH, owb, NH, ob, out, ND, ND, NH, rmap);
}

// Round 6
// 761.876 us; speedup vs baseline: 1.4030x; 1.0305x over previous
//
#include <hip/hip_runtime.h>
#include <math.h>

#define NB 16
#define NL 4096
#define ND 192
#define NH 384
#define NS 16
#define NTK 17
#define NIR 128
#define NR 24
#define NHH 64
#define NWW 64
#define NCHUNKS 32
#define CHUNKLEN 128
#define NTOK (NB*NL)

typedef __attribute__((ext_vector_type(8))) short short8;
typedef __attribute__((ext_vector_type(4))) float floatx4;

__device__ __forceinline__ float gelu_tanh(float x){
  return 0.5f*x*(1.0f + tanhf(0.7978845608028654f*(x + 0.044715f*x*x*x)));
}
__device__ __forceinline__ float softplus_f(float x){
  return (x > 20.0f) ? x : log1pf(expf(x));
}
__device__ __forceinline__ short f2bf(float f){
  unsigned u = __float_as_uint(f);
  unsigned r = (u + 0x7fffu + ((u >> 16) & 1u)) >> 16;
  return (short)r;
}

union Pack8 { uint4 v; short s[8]; };

// full_emb = embB(17x128) @ token_weight(128x16)
__global__ void k_emb(const float* __restrict__ embB, const float* __restrict__ tw,
                      float* __restrict__ fe){
  for (int o = threadIdx.x; o < NTK*NS; o += 256){
    int t = o / NS, s = o % NS;
    float acc = 0.f;
    for (int i = 0; i < NIR; ++i) acc += embB[t*NIR+i]*tw[i*NS+s];
    fe[o] = acc;
  }
}

// convert weights to bf16 (dtw zero-padded K 24->32)
__global__ void k_cvtw(const float* __restrict__ inw, const float* __restrict__ ow,
                       const float* __restrict__ xpw, const float* __restrict__ dtw,
                       short* __restrict__ inwb, short* __restrict__ owb,
                       short* __restrict__ xpwb, short* __restrict__ dtwb){
  int i = blockIdx.x*256 + threadIdx.x;
  int stride = gridDim.x*256;
  for (int p = i; p < NH*ND; p += stride) inwb[p] = f2bf(inw[p]);
  for (int p = i; p < ND*NH; p += stride) owb[p] = f2bf(ow[p]);
  for (int p = i; p < 56*NH; p += stride) xpwb[p] = f2bf(xpw[p]);
  for (int p = i; p < NH*32; p += stride){
    int r = p >> 5, c = p & 31;
    dtwb[p] = (c < NR) ? f2bf(dtw[r*NR + c]) : (short)0;
  }
}

// fp32 GEMM (routing layer only: argmax sensitivity forbids bf16 here)
template<int EPI>
__global__ __launch_bounds__(256) void k_gemm(const float* __restrict__ A, int lda,
    const float* __restrict__ W, int ldw, const float* __restrict__ bias,
    float* __restrict__ C, int ldc, int N, int K){
  __shared__ float As[16][68];
  __shared__ float Ws[16][68];
  int tid = threadIdx.x;
  int m0 = blockIdx.x*64, n0 = blockIdx.y*64;
  int tx = tid & 15, ty = tid >> 4;
  int srow = tid >> 2, skseg = (tid & 3)*4;
  float acc[4][4] = {};
  for (int k0 = 0; k0 < K; k0 += 16){
    {
      const float* ap = A + (size_t)(m0+srow)*lda + k0 + skseg;
      float4 v = *(const float4*)ap;
      As[skseg+0][srow]=v.x; As[skseg+1][srow]=v.y;
      As[skseg+2][srow]=v.z; As[skseg+3][srow]=v.w;
    }
    {
      float4 v = {0.f,0.f,0.f,0.f};
      if (n0 + srow < N) v = *(const float4*)(W + (size_t)(n0+srow)*ldw + k0 + skseg);
      Ws[skseg+0][srow]=v.x; Ws[skseg+1][srow]=v.y;
      Ws[skseg+2][srow]=v.z; Ws[skseg+3][srow]=v.w;
    }
    __syncthreads();
    #pragma unroll
    for (int kk = 0; kk < 16; ++kk){
      float4 av = *(const float4*)&As[kk][ty*4];
      float4 wv = *(const float4*)&Ws[kk][tx*4];
      acc[0][0] += av.x*wv.x; acc[0][1] += av.x*wv.y;
      acc[0][2] += av.x*wv.z; acc[0][3] += av.x*wv.w;
      acc[1][0] += av.y*wv.x; acc[1][1] += av.y*wv.y;
      acc[1][2] += av.y*wv.z; acc[1][3] += av.y*wv.w;
      acc[2][0] += av.z*wv.x; acc[2][1] += av.z*wv.y;
      acc[2][2] += av.z*wv.z; acc[2][3] += av.z*wv.w;
      acc[3][0] += av.w*wv.x; acc[3][1] += av.w*wv.y;
      acc[3][2] += av.w*wv.z; acc[3][3] += av.w*wv.w;
    }
    __syncthreads();
  }
  #pragma unroll
  for (int i = 0; i < 4; ++i){
    int m = m0 + ty*4 + i;
    #pragma unroll
    for (int j = 0; j < 4; ++j){
      int n = n0 + tx*4 + j;
      if (n < N){
        float v = acc[i][j] + (bias ? bias[n] : 0.f);
        if (EPI==1) v = gelu_tanh(v);
        C[(size_t)m*ldc + n] = v;
      }
    }
  }
}

// bf16 MFMA GEMM: C(MxN) = A(MxK) @ W(NxK bf16)^T + bias.
// A fp32 (AF32=1, converted during LDS staging) or bf16 (AF32=0).
// LNA=1: apply per-row layernorm (mean/rstd precomputed; g/b over K) during staging.
// EPI: 0 none, 2 softplus, 3 row-scatter via remap
template<int EPI, int AF32, int LNA>
__global__ __launch_bounds__(256) void k_mfma(const void* __restrict__ Aptr, int lda,
    const short* __restrict__ Wbf, int ldw, const float* __restrict__ bias,
    float* __restrict__ C, int ldc, int N, int K, const int* __restrict__ remap,
    const float* __restrict__ lnm, const float* __restrict__ lnr,
    const float* __restrict__ lng, const float* __restrict__ lnb){
  __shared__ short As[128*40];   // stride 40 shorts = 80B: 16B-aligned b128, 2-way banks (free)
  __shared__ short Bs[64*40];
  int tid = threadIdx.x;
  int m0 = blockIdx.x*128, n0 = blockIdx.y*64;
  int w = tid >> 6, lane = tid & 63;
  int lq = lane >> 4, lr = lane & 15;
  floatx4 acc[2][4];
  #pragma unroll
  for (int i = 0; i < 2; ++i)
    #pragma unroll
    for (int j = 0; j < 4; ++j) acc[i][j] = (floatx4){0.f,0.f,0.f,0.f};
  int ar = tid >> 1, aq = (tid & 1)*2;   // A: each thread stages 16 elts of one row
  int br = tid >> 2, bq = tid & 3;       // B: each thread stages 8 elts of one row
  float mr = 0.f, rr = 0.f;
  if (LNA){ mr = lnm[m0+ar]; rr = lnr[m0+ar]; }
  for (int k0 = 0; k0 < K; k0 += 32){
    Pack8 sa0, sa1;
    if (AF32){
      const float* ap = (const float*)Aptr + (size_t)(m0+ar)*lda + k0 + aq*8;
      float f[16];
      float4 f0 = *(const float4*)(ap);
      float4 f1 = *(const float4*)(ap+4);
      float4 f2 = *(const float4*)(ap+8);
      float4 f3 = *(const float4*)(ap+12);
      f[0]=f0.x; f[1]=f0.y; f[2]=f0.z; f[3]=f0.w;
      f[4]=f1.x; f[5]=f1.y; f[6]=f1.z; f[7]=f1.w;
      f[8]=f2.x; f[9]=f2.y; f[10]=f2.z; f[11]=f2.w;
      f[12]=f3.x; f[13]=f3.y; f[14]=f3.z; f[15]=f3.w;
      if (LNA){
        const float* gp = lng + k0 + aq*8;
        const float* bp = lnb + k0 + aq*8;
        #pragma unroll
        for (int j = 0; j < 16; ++j) f[j] = (f[j]-mr)*rr*gp[j] + bp[j];
      }
      #pragma unroll
      for (int j = 0; j < 8; ++j){ sa0.s[j] = f2bf(f[j]); sa1.s[j] = f2bf(f[8+j]); }
    } else {
      const short* ap = (const short*)Aptr + (size_t)(m0+ar)*lda + k0 + aq*8;
      sa0.v = *(const uint4*)ap;
      sa1.v = *(const uint4*)(ap + 8);
    }
    uint4 bv = {0u,0u,0u,0u};
    if (n0 + br < N) bv = *(const uint4*)(Wbf + (size_t)(n0+br)*ldw + k0 + bq*8);
    __syncthreads();
    *(uint4*)&As[ar*40 + aq*8]     = sa0.v;
    *(uint4*)&As[ar*40 + aq*8 + 8] = sa1.v;
    *(uint4*)&Bs[br*40 + bq*8]     = bv;
    __syncthreads();
    short8 a0 = *(const short8*)&As[(w*32      + lr)*40 + lq*8];
    short8 a1 = *(const short8*)&As[(w*32 + 16 + lr)*40 + lq*8];
    short8 b0 = *(const short8*)&Bs[(     lr)*40 + lq*8];
    short8 b1 = *(const short8*)&Bs[(16 + lr)*40 + lq*8];
    short8 b2 = *(const short8*)&Bs[(32 + lr)*40 + lq*8];
    short8 b3 = *(const short8*)&Bs[(48 + lr)*40 + lq*8];
    acc[0][0] = __builtin_amdgcn_mfma_f32_16x16x32_bf16(a0, b0, acc[0][0], 0,0,0);
    acc[0][1] = __builtin_amdgcn_mfma_f32_16x16x32_bf16(a0, b1, acc[0][1], 0,0,0);
    acc[0][2] = __builtin_amdgcn_mfma_f32_16x16x32_bf16(a0, b2, acc[0][2], 0,0,0);
    acc[0][3] = __builtin_amdgcn_mfma_f32_16x16x32_bf16(a0, b3, acc[0][3], 0,0,0);
    acc[1][0] = __builtin_amdgcn_mfma_f32_16x16x32_bf16(a1, b0, acc[1][0], 0,0,0);
    acc[1][1] = __builtin_amdgcn_mfma_f32_16x16x32_bf16(a1, b1, acc[1][1], 0,0,0);
    acc[1][2] = __builtin_amdgcn_mfma_f32_16x16x32_bf16(a1, b2, acc[1][2], 0,0,0);
    acc[1][3] = __builtin_amdgcn_mfma_f32_16x16x32_bf16(a1, b3, acc[1][3], 0,0,0);
  }
  // C/D layout (verified m89): col = lane&15, row = (lane>>4)*4 + reg
  #pragma unroll
  for (int mt = 0; mt < 2; ++mt){
    #pragma unroll
    for (int r = 0; r < 4; ++r){
      int m = m0 + w*32 + mt*16 + lq*4 + r;
      int orow = (EPI==3) ? remap[m] : m;
      #pragma unroll
      for (int nt = 0; nt < 4; ++nt){
        int n = n0 + nt*16 + lr;
        if (n < N){
          float v = acc[mt][nt][r] + (bias ? bias[n] : 0.f);
          if (EPI==2) v = softplus_f(v);
          C[(size_t)orow*ldc + n] = v;
        }
      }
    }
  }
}

// logits = hmid @ w2^T + b2 + gumbel ; idx = argmax (first occurrence)
__global__ __launch_bounds__(256) void k_argmax(const float* __restrict__ hmid,
    const float* __restrict__ w2, const float* __restrict__ b2,
    const float* __restrict__ gumbel, int* __restrict__ idx){
  int g = blockIdx.x*256 + threadIdx.x;
  float hm[64];
  const float4* hp = (const float4*)(hmid + (size_t)g*64);
  #pragma unroll
  for (int i = 0; i < 16; ++i){
    float4 v = hp[i];
    hm[i*4+0]=v.x; hm[i*4+1]=v.y; hm[i*4+2]=v.z; hm[i*4+3]=v.w;
  }
  float best = -INFINITY; int bi = 0;
  for (int c = 0; c < NTK; ++c){
    float s = b2[c] + gumbel[(size_t)g*NTK + c];
    #pragma unroll
    for (int j = 0; j < 64; ++j) s += hm[j]*w2[c*64+j];
    if (s > best){ best = s; bi = c; }
  }
  idx[g] = bi;
}

// stable counting sort per batch over 17 keys
__global__ __launch_bounds__(256) void k_sort(const int* __restrict__ idx,
    int* __restrict__ rmap, int* __restrict__ inv){
  int b = blockIdx.x, t = threadIdx.x;
  __shared__ int hist[NTK][256];
  __shared__ int tot[NTK];
  __shared__ int keybase[NTK];
  int keys[16];
  const int* ip = idx + b*NL + t*16;
  #pragma unroll
  for (int i = 0; i < 16; ++i) keys[i] = ip[i];
  #pragma unroll
  for (int k = 0; k < NTK; ++k){
    int c = 0;
    #pragma unroll
    for (int i = 0; i < 16; ++i) c += (keys[i]==k) ? 1 : 0;
    hist[k][t] = c;
  }
  __syncthreads();
  if (t < NTK){
    int run = 0;
    for (int j = 0; j < 256; ++j){ int v = hist[t][j]; hist[t][j] = run; run += v; }
    tot[t] = run;
  }
  __syncthreads();
  if (t == 0){
    int base = 0;
    for (int k = 0; k < NTK; ++k){ keybase[k] = base; base += tot[k]; }
  }
  __syncthreads();
  #pragma unroll
  for (int i = 0; i < 16; ++i){
    int k = keys[i];
    int cb = 0;
    #pragma unroll
    for (int j = 0; j < 16; ++j) cb += (j < i && keys[j]==k) ? 1 : 0;
    int pos = keybase[k] + hist[k][t] + cb;
    rmap[b*NL + pos] = b*NL + t*16 + i;
    inv[b*NL + t*16 + i] = pos;
  }
}

// depthwise 3x3 SAME conv + sigmoid gate; scatter rows to sorted order
__global__ __launch_bounds__(256) void k_cpe(const float* __restrict__ xi,
    const float* __restrict__ cw, const float* __restrict__ cb,
    const int* __restrict__ inv, float* __restrict__ us){
  int bl = blockIdx.x;
  int cg = bl & 3;
  int xt = (bl>>2) & 7;
  int yt = (bl>>5) & 7;
  int b  = bl >> 8;
  __shared__ float tile[10*10*96];
  int c0 = cg*96;
  for (int p = threadIdx.x; p < 10*10*96; p += 256){
    int c = p % 96; int xx = (p/96) % 10; int yy = p/960;
    int gy = yt*8 + yy - 1, gx = xt*8 + xx - 1;
    float v = 0.f;
    if (gy >= 0 && gy < NHH && gx >= 0 && gx < NWW)
      v = xi[((size_t)(b*NL + gy*NWW + gx))*NH + c0 + c];
    tile[p] = v;
  }
  __syncthreads();
  for (int p = threadIdx.x; p < 8*8*96; p += 256){
    int c = p % 96; int xx = (p/96) % 8; int yy = p/768;
    int ch = c0 + c;
    float acc = cb[ch];
    #pragma unroll
    for (int dy = 0; dy < 3; ++dy)
      #pragma unroll
      for (int dx = 0; dx < 3; ++dx)
        acc += tile[((yy+dy)*10 + (xx+dx))*96 + c] * cw[ch*9 + dy*3 + dx];
    float center = tile[((yy+1)*10 + (xx+1))*96 + c];
    float gate = 1.f/(1.f + expf(-acc));
    int l = (yt*8+yy)*NWW + xt*8+xx;
    int pos = inv[b*NL + l];
    us[((size_t)(b*NL + pos))*NH + ch] = center*gate;
  }
}

// split x_dbl into Bs, Cs (+prompt), and dts as zero-padded bf16 (K=32)
__global__ __launch_bounds__(256) void k_bc(const float* __restrict__ dbl,
    const int* __restrict__ idx, const float* __restrict__ fe,
    const int* __restrict__ gt, float* __restrict__ Bsb, float* __restrict__ Csb,
    short* __restrict__ dtsb){
  int g = blockIdx.x*256 + threadIdx.x;
  const float* dr = dbl + (size_t)g*56;
  int id = idx[g];
  int gather = gt[0];
  #pragma unroll
  for (int n = 0; n < NR; ++n) dtsb[(size_t)g*32 + n] = f2bf(dr[n]);
  #pragma unroll
  for (int n = NR; n < 32; ++n) dtsb[(size_t)g*32 + n] = 0;
  #pragma unroll
  for (int n = 0; n < NS; ++n){
    Bsb[(size_t)g*NS + n] = dr[24+n];
    float c = dr[40+n];
    if (gather != 0) c += fe[id*NS + n];
    Csb[(size_t)g*NS + n] = c;
  }
}

// decay helper: a[n] = exp(dlt*An[n]); pw path: binary powers of r (depth 5, not 15).
__device__ __forceinline__ void decay16(bool pw, float dlt, const float* An, float* a){
  if (pw){
    float r  = __expf(dlt*An[0]);
    float r2 = r*r;
    float r3 = r2*r;
    float r4 = r2*r2;
    float r8 = r4*r4;
    float r12 = r8*r4;
    a[0]=r;     a[1]=r2;     a[2]=r3;     a[3]=r4;
    a[4]=r4*r;  a[5]=r4*r2;  a[6]=r4*r3;  a[7]=r8;
    a[8]=r8*r;  a[9]=r8*r2;  a[10]=r8*r3; a[11]=r12;
    a[12]=r12*r; a[13]=r12*r2; a[14]=r12*r3; a[15]=r8*r8;
  } else {
    #pragma unroll
    for (int n = 0; n < NS; ++n) a[n] = __expf(dlt*An[n]);
  }
}
__device__ __forceinline__ bool pwcheck(const float* An){
  bool pw = true;
  #pragma unroll
  for (int n = 1; n < NS; ++n)
    pw = pw && (fabsf(An[n] - (n+1)*An[0]) <= 1e-4f*fabsf(An[n]));
  return pw;
}

// scan phase 1: per (b,chunk,d): Aprod[n] = exp(An[n]*sum(dlt)), Boff[n] = local scan end
__global__ __launch_bounds__(384) void k_scan1(const float* __restrict__ delta,
    const float* __restrict__ us, const float* __restrict__ Bsb,
    const float* __restrict__ A_logs, float* __restrict__ Aprod, float* __restrict__ Boff){
  int bc = blockIdx.x;
  int c = bc & (NCHUNKS-1);
  int b = bc >> 5;
  int d = threadIdx.x;
  __shared__ float Bsh[CHUNKLEN*NS];
  int base = b*NL + c*CHUNKLEN;
  for (int p = d; p < CHUNKLEN*NS; p += 384) Bsh[p] = Bsb[(size_t)base*NS + p];
  float An[NS];
  #pragma unroll
  for (int n = 0; n < NS; ++n) An[n] = -expf(A_logs[d*NS + n]);
  bool pw = pwcheck(An);
  float h[NS];
  #pragma unroll
  for (int n = 0; n < NS; ++n) h[n]=0.f;
  float sd = 0.f;
  __syncthreads();
  #pragma unroll 2
  for (int s = 0; s < CHUNKLEN; ++s){
    size_t gi = (size_t)(base + s)*NH + d;
    float dlt = delta[gi];
    float uv = us[gi];
    float du = dlt*uv;
    sd += dlt;
    float a[NS];
    decay16(pw, dlt, An, a);
    #pragma unroll
    for (int n = 0; n < NS; ++n) h[n] = a[n]*h[n] + du*Bsh[s*NS+n];
  }
  // Aprod = product of per-step decays = exp(An[n] * sum dlt)  (exact identity)
  float ap[NS];
  decay16(pw, sd, An, ap);
  size_t o = ((size_t)bc*NH + d)*NS;
  #pragma unroll
  for (int n = 0; n < NS; ++n){ Aprod[o+n]=ap[n]; Boff[o+n]=h[n]; }
}

// scan phase 2: compose chunk summaries; hinit written IN PLACE into Boff
__global__ __launch_bounds__(256) void k_scan2(const float* __restrict__ Aprod,
    float* __restrict__ Boff){
  int i = blockIdx.x*256 + threadIdx.x;
  int dn = i % (NH*NS);
  int b = i / (NH*NS);
  float h = 0.f;
  for (int c = 0; c < NCHUNKS; ++c){
    size_t o = ((size_t)(b*NCHUNKS + c)*NH*NS) + dn;
    float a = Aprod[o];
    float bo = Boff[o];
    Boff[o] = h;
    h = a*h + bo;
  }
}

// scan phase 3 (hinit = Boff after k_scan2)
__global__ __launch_bounds__(384) void k_scan3(const float* __restrict__ delta,
    const float* __restrict__ Bsb, const float* __restrict__ Csb,
    const float* __restrict__ A_logs, const float* __restrict__ Ds,
    const float* __restrict__ hinit, float* __restrict__ us){
  int bc = blockIdx.x;
  int c = bc & (NCHUNKS-1);
  int b = bc >> 5;
  int d = threadIdx.x;
  __shared__ float Bsh[CHUNKLEN*NS];
  __shared__ float Csh[CHUNKLEN*NS];
  int base = b*NL + c*CHUNKLEN;
  for (int p = d; p < CHUNKLEN*NS; p += 384){
    Bsh[p] = Bsb[(size_t)base*NS + p];
    Csh[p] = Csb[(size_t)base*NS + p];
  }
  float An[NS];
  #pragma unroll
  for (int n = 0; n < NS; ++n) An[n] = -expf(A_logs[d*NS + n]);
  bool pw = pwcheck(An);
  float h[NS];
  size_t ho = ((size_t)bc*NH + d)*NS;
  #pragma unroll
  for (int n = 0; n < NS; ++n) h[n] = hinit[ho + n];
  float Dd = Ds[d];
  __syncthreads();
  #pragma unroll 2
  for (int s = 0; s < CHUNKLEN; ++s){
    size_t gi = (size_t)(base + s)*NH + d;
    float dlt = delta[gi];
    float uv = us[gi];
    float du = dlt*uv;
    float a[NS];
    decay16(pw, dlt, An, a);
    float y = 0.f;
    #pragma unroll
    for (int n = 0; n < NS; ++n){
      h[n] = a[n]*h[n] + du*Bsh[s*NS+n];
      y += h[n]*Csh[s*NS+n];
    }
    us[gi] = y + uv*Dd;
  }
}

// layernorm stats over hidden (384): mean/rstd per token; one wave per token
__global__ __launch_bounds__(256) void k_lnstat(const float* __restrict__ y,
    float* __restrict__ mean, float* __restrict__ rstd){
  int g = blockIdx.x*4 + (threadIdx.x >> 6);
  int lane = threadIdx.x & 63;
  size_t ro = (size_t)g*NH;
  float v[6];
  #pragma unroll
  for (int i = 0; i < 6; ++i) v[i] = y[ro + i*64 + lane];
  float s = 0.f;
  #pragma unroll
  for (int i = 0; i < 6; ++i) s += v[i];
  #pragma unroll
  for (int off = 32; off > 0; off >>= 1) s += __shfl_xor(s, off);
  float mu = s * (1.f/NH);
  float vs = 0.f;
  #pragma unroll
  for (int i = 0; i < 6; ++i){ float d = v[i]-mu; vs += d*d; }
  #pragma unroll
  for (int off = 32; off > 0; off >>= 1) vs += __shfl_xor(vs, off);
  float rs = rsqrtf(vs*(1.f/NH) + 1e-5f);
  if (lane == 0){ mean[g] = mu; rstd[g] = rs; }
}

extern "C" void kernel_launch(void* const* d_in, const int* in_sizes, int n_in,
                              void* d_out, int out_size, void* d_ws, size_t ws_size,
                              hipStream_t stream){
  const float* x      = (const float*)d_in[0];
  const float* tw     = (const float*)d_in[1];
  const float* gumbel = (const float*)d_in[2];
  const float* embB   = (const float*)d_in[3];
  const float* rw1    = (const float*)d_in[4];
  const float* rb1    = (const float*)d_in[5];
  const float* rw2    = (const float*)d_in[6];
  const float* rb2    = (const float*)d_in[7];
  const float* inw    = (const float*)d_in[8];
  const float* inb    = (const float*)d_in[9];
  const float* cw     = (const float*)d_in[10];
  const float* cb     = (const float*)d_in[11];
  const float* xpw    = (const float*)d_in[12];
  const float* dtw    = (const float*)d_in[13];
  const float* dtb    = (const float*)d_in[14];
  const float* A_logs = (const float*)d_in[15];
  const float* Ds     = (const float*)d_in[16];
  const float* ng     = (const float*)d_in[17];
  const float* nbv    = (const float*)d_in[18];
  const float* ow     = (const float*)d_in[19];
  const float* ob     = (const float*)d_in[20];
  const int*   gt     = (const int*)d_in[23];
  float* out = (float*)d_out;

  // Workspace layout — IDENTICAL to round 3/5 (known-good through full harness).
  float* ws = (float*)d_ws;
  size_t o = 0;
  float* fe   = ws + o; o += 512;
  int* idx    = (int*)(ws + o); o += NTOK;   // dead after k_bc -> reused as LN mean
  int* rmap   = (int*)(ws + o); o += NTOK;
  int* inv    = (int*)(ws + o); o += NTOK;   // dead after k_cpe -> reused as LN rstd
  float* hmid = ws + o; o += (size_t)NTOK*64;   // reused as dbl (NTOK*56)
  float* xi   = ws + o; o += (size_t)NTOK*NH;   // reused as delta
  float* us   = ws + o; o += (size_t)NTOK*NH;   // u -> y (stays pre-LN; LN fused in out_proj)
  float* Bsb  = ws + o; o += (size_t)NTOK*NS;
  float* Csb  = ws + o; o += (size_t)NTOK*NS;
  float* Apr  = ws + o; o += (size_t)NB*NCHUNKS*NH*NS;  // dtsb aliases this (disjoint lifetime)
  float* Bof  = ws + o; o += (size_t)NB*NCHUNKS*NH*NS;  // becomes hinit in-place via k_scan2
  short* inwb = (short*)(ws + o); o += (NH*ND)/2;
  short* owb  = (short*)(ws + o); o += (ND*NH)/2;
  short* xpwb = (short*)(ws + o); o += (56*NH)/2 + 32;
  short* dtwb = (short*)(ws + o); o += (NH*32)/2;
  float* dbl = hmid;
  float* delta = xi;
  short* dtsb = (short*)Apr;   // NTOK*32 shorts = 4 MB, dies before scan1 writes Apr
  float* lnmean = (float*)idx; // NTOK floats, idx dead by LN time
  float* lnrstd = (float*)inv; // NTOK floats, inv dead by LN time

  k_emb<<<1,256,0,stream>>>(embB, tw, fe);
  k_cvtw<<<64,256,0,stream>>>(inw, ow, xpw, dtw, inwb, owb, xpwb, dtwb);
  // routing MLP layer 1 (fp32: argmax margins too tight for bf16)
  k_gemm<1><<<dim3(NTOK/64,1),256,0,stream>>>(x, ND, rw1, ND, rb1, hmid, 64, 64, ND);
  k_argmax<<<NTOK/256,256,0,stream>>>(hmid, rw2, rb2, gumbel, idx);
  k_sort<<<NB,256,0,stream>>>(idx, rmap, inv);
  // in_proj: xi = x @ inw^T + inb (bf16 MFMA, fp32 A converted in staging)
  k_mfma<0,1,0><<<dim3(NTOK/128,6),256,0,stream>>>(x, ND, inwb, ND, inb, xi, NH, NH, ND,
      nullptr, nullptr, nullptr, nullptr, nullptr);
  // CPE gate + scatter to sorted order
  k_cpe<<<NB*64*4,256,0,stream>>>(xi, cw, cb, inv, us);
  // x_dbl = us @ xpw^T (bf16 MFMA, N=56)
  k_mfma<0,1,0><<<dim3(NTOK/128,1),256,0,stream>>>(us, NH, xpwb, NH, nullptr, dbl, 56, 56, NH,
      nullptr, nullptr, nullptr, nullptr, nullptr);
  k_bc<<<NTOK/256,256,0,stream>>>(dbl, idx, fe, gt, Bsb, Csb, dtsb);
  // delta = softplus(dts @ dtw^T + dtb)  (bf16 MFMA, K=32 padded)
  k_mfma<2,0,0><<<dim3(NTOK/128,6),256,0,stream>>>(dtsb, 32, dtwb, 32, dtb, delta, NH, NH, 32,
      nullptr, nullptr, nullptr, nullptr, nullptr);
  k_scan1<<<NB*NCHUNKS,384,0,stream>>>(delta, us, Bsb, A_logs, Apr, Bof);
  k_scan2<<<(NB*NH*NS)/256,256,0,stream>>>(Apr, Bof);
  k_scan3<<<NB*NCHUNKS,384,0,stream>>>(delta, Bsb, Csb, A_logs, Ds, Bof, us);
  // layernorm stats only; normalization fused into out_proj A-staging
  k_lnstat<<<NTOK/4,256,0,stream>>>(us, lnmean, lnrstd);
  // out_proj (+fused LN) + scatter back to original token order
  k_mfma<3,1,1><<<dim3(NTOK/128,3),256,0,stream>>>(us, NH, owb, NH, ob, out, ND, ND, NH,
      rmap, lnmean, lnrstd, ng, nbv);
}

// Round 7
// 758.411 us; speedup vs baseline: 1.4094x; 1.0046x over previous
//
#include <hip/hip_runtime.h>
#include <math.h>

#define NB 16
#define NL 4096
#define ND 192
#define NH 384
#define NS 16
#define NTK 17
#define NIR 128
#define NR 24
#define NHH 64
#define NWW 64
#define NCHUNKS 32
#define CHUNKLEN 128
#define NTOK (NB*NL)

typedef __attribute__((ext_vector_type(8))) short short8;
typedef __attribute__((ext_vector_type(4))) float floatx4;

__device__ __forceinline__ float gelu_tanh(float x){
  return 0.5f*x*(1.0f + tanhf(0.7978845608028654f*(x + 0.044715f*x*x*x)));
}
__device__ __forceinline__ float softplus_f(float x){
  return (x > 20.0f) ? x : log1pf(expf(x));
}
__device__ __forceinline__ short f2bf(float f){
  unsigned u = __float_as_uint(f);
  unsigned r = (u + 0x7fffu + ((u >> 16) & 1u)) >> 16;
  return (short)r;
}

union Pack8 { uint4 v; short s[8]; };

// full_emb = embB(17x128) @ token_weight(128x16)
__global__ void k_emb(const float* __restrict__ embB, const float* __restrict__ tw,
                      float* __restrict__ fe){
  for (int o = threadIdx.x; o < NTK*NS; o += 256){
    int t = o / NS, s = o % NS;
    float acc = 0.f;
    for (int i = 0; i < NIR; ++i) acc += embB[t*NIR+i]*tw[i*NS+s];
    fe[o] = acc;
  }
}

// convert weights to bf16 (dtw zero-padded K 24->32)
__global__ void k_cvtw(const float* __restrict__ inw, const float* __restrict__ ow,
                       const float* __restrict__ xpw, const float* __restrict__ dtw,
                       short* __restrict__ inwb, short* __restrict__ owb,
                       short* __restrict__ xpwb, short* __restrict__ dtwb){
  int i = blockIdx.x*256 + threadIdx.x;
  int stride = gridDim.x*256;
  for (int p = i; p < NH*ND; p += stride) inwb[p] = f2bf(inw[p]);
  for (int p = i; p < ND*NH; p += stride) owb[p] = f2bf(ow[p]);
  for (int p = i; p < 56*NH; p += stride) xpwb[p] = f2bf(xpw[p]);
  for (int p = i; p < NH*32; p += stride){
    int r = p >> 5, c = p & 31;
    dtwb[p] = (c < NR) ? f2bf(dtw[r*NR + c]) : (short)0;
  }
}

// fp32 GEMM (routing layer only: argmax sensitivity forbids bf16 here)
template<int EPI>
__global__ __launch_bounds__(256) void k_gemm(const float* __restrict__ A, int lda,
    const float* __restrict__ W, int ldw, const float* __restrict__ bias,
    float* __restrict__ C, int ldc, int N, int K){
  __shared__ float As[16][68];
  __shared__ float Ws[16][68];
  int tid = threadIdx.x;
  int m0 = blockIdx.x*64, n0 = blockIdx.y*64;
  int tx = tid & 15, ty = tid >> 4;
  int srow = tid >> 2, skseg = (tid & 3)*4;
  float acc[4][4] = {};
  for (int k0 = 0; k0 < K; k0 += 16){
    {
      const float* ap = A + (size_t)(m0+srow)*lda + k0 + skseg;
      float4 v = *(const float4*)ap;
      As[skseg+0][srow]=v.x; As[skseg+1][srow]=v.y;
      As[skseg+2][srow]=v.z; As[skseg+3][srow]=v.w;
    }
    {
      float4 v = {0.f,0.f,0.f,0.f};
      if (n0 + srow < N) v = *(const float4*)(W + (size_t)(n0+srow)*ldw + k0 + skseg);
      Ws[skseg+0][srow]=v.x; Ws[skseg+1][srow]=v.y;
      Ws[skseg+2][srow]=v.z; Ws[skseg+3][srow]=v.w;
    }
    __syncthreads();
    #pragma unroll
    for (int kk = 0; kk < 16; ++kk){
      float4 av = *(const float4*)&As[kk][ty*4];
      float4 wv = *(const float4*)&Ws[kk][tx*4];
      acc[0][0] += av.x*wv.x; acc[0][1] += av.x*wv.y;
      acc[0][2] += av.x*wv.z; acc[0][3] += av.x*wv.w;
      acc[1][0] += av.y*wv.x; acc[1][1] += av.y*wv.y;
      acc[1][2] += av.y*wv.z; acc[1][3] += av.y*wv.w;
      acc[2][0] += av.z*wv.x; acc[2][1] += av.z*wv.y;
      acc[2][2] += av.z*wv.z; acc[2][3] += av.z*wv.w;
      acc[3][0] += av.w*wv.x; acc[3][1] += av.w*wv.y;
      acc[3][2] += av.w*wv.z; acc[3][3] += av.w*wv.w;
    }
    __syncthreads();
  }
  #pragma unroll
  for (int i = 0; i < 4; ++i){
    int m = m0 + ty*4 + i;
    #pragma unroll
    for (int j = 0; j < 4; ++j){
      int n = n0 + tx*4 + j;
      if (n < N){
        float v = acc[i][j] + (bias ? bias[n] : 0.f);
        if (EPI==1) v = gelu_tanh(v);
        C[(size_t)m*ldc + n] = v;
      }
    }
  }
}

// bf16 MFMA GEMM: C(MxN) = A(MxK) @ W(NxK bf16)^T + bias.
// A fp32 (AF32=1, converted during LDS staging) or bf16 (AF32=0).
// LNA=1: apply per-row layernorm (mean/rstd precomputed; g/b over K) during staging.
// EPI: 0 none, 2 softplus, 3 row-scatter via remap
template<int EPI, int AF32, int LNA>
__global__ __launch_bounds__(256) void k_mfma(const void* __restrict__ Aptr, int lda,
    const short* __restrict__ Wbf, int ldw, const float* __restrict__ bias,
    float* __restrict__ C, int ldc, int N, int K, const int* __restrict__ remap,
    const float* __restrict__ lnm, const float* __restrict__ lnr,
    const float* __restrict__ lng, const float* __restrict__ lnb){
  __shared__ short As[128*40];   // stride 40 shorts = 80B: 16B-aligned b128, 2-way banks (free)
  __shared__ short Bs[64*40];
  int tid = threadIdx.x;
  int m0 = blockIdx.x*128, n0 = blockIdx.y*64;
  int w = tid >> 6, lane = tid & 63;
  int lq = lane >> 4, lr = lane & 15;
  floatx4 acc[2][4];
  #pragma unroll
  for (int i = 0; i < 2; ++i)
    #pragma unroll
    for (int j = 0; j < 4; ++j) acc[i][j] = (floatx4){0.f,0.f,0.f,0.f};
  int ar = tid >> 1, aq = (tid & 1)*2;   // A: each thread stages 16 elts of one row
  int br = tid >> 2, bq = tid & 3;       // B: each thread stages 8 elts of one row
  float mr = 0.f, rr = 0.f;
  if (LNA){ mr = lnm[m0+ar]; rr = lnr[m0+ar]; }
  for (int k0 = 0; k0 < K; k0 += 32){
    Pack8 sa0, sa1;
    if (AF32){
      const float* ap = (const float*)Aptr + (size_t)(m0+ar)*lda + k0 + aq*8;
      float f[16];
      float4 f0 = *(const float4*)(ap);
      float4 f1 = *(const float4*)(ap+4);
      float4 f2 = *(const float4*)(ap+8);
      float4 f3 = *(const float4*)(ap+12);
      f[0]=f0.x; f[1]=f0.y; f[2]=f0.z; f[3]=f0.w;
      f[4]=f1.x; f[5]=f1.y; f[6]=f1.z; f[7]=f1.w;
      f[8]=f2.x; f[9]=f2.y; f[10]=f2.z; f[11]=f2.w;
      f[12]=f3.x; f[13]=f3.y; f[14]=f3.z; f[15]=f3.w;
      if (LNA){
        const float* gp = lng + k0 + aq*8;
        const float* bp = lnb + k0 + aq*8;
        #pragma unroll
        for (int j = 0; j < 16; ++j) f[j] = (f[j]-mr)*rr*gp[j] + bp[j];
      }
      #pragma unroll
      for (int j = 0; j < 8; ++j){ sa0.s[j] = f2bf(f[j]); sa1.s[j] = f2bf(f[8+j]); }
    } else {
      const short* ap = (const short*)Aptr + (size_t)(m0+ar)*lda + k0 + aq*8;
      sa0.v = *(const uint4*)ap;
      sa1.v = *(const uint4*)(ap + 8);
    }
    uint4 bv = {0u,0u,0u,0u};
    if (n0 + br < N) bv = *(const uint4*)(Wbf + (size_t)(n0+br)*ldw + k0 + bq*8);
    __syncthreads();
    *(uint4*)&As[ar*40 + aq*8]     = sa0.v;
    *(uint4*)&As[ar*40 + aq*8 + 8] = sa1.v;
    *(uint4*)&Bs[br*40 + bq*8]     = bv;
    __syncthreads();
    short8 a0 = *(const short8*)&As[(w*32      + lr)*40 + lq*8];
    short8 a1 = *(const short8*)&As[(w*32 + 16 + lr)*40 + lq*8];
    short8 b0 = *(const short8*)&Bs[(     lr)*40 + lq*8];
    short8 b1 = *(const short8*)&Bs[(16 + lr)*40 + lq*8];
    short8 b2 = *(const short8*)&Bs[(32 + lr)*40 + lq*8];
    short8 b3 = *(const short8*)&Bs[(48 + lr)*40 + lq*8];
    acc[0][0] = __builtin_amdgcn_mfma_f32_16x16x32_bf16(a0, b0, acc[0][0], 0,0,0);
    acc[0][1] = __builtin_amdgcn_mfma_f32_16x16x32_bf16(a0, b1, acc[0][1], 0,0,0);
    acc[0][2] = __builtin_amdgcn_mfma_f32_16x16x32_bf16(a0, b2, acc[0][2], 0,0,0);
    acc[0][3] = __builtin_amdgcn_mfma_f32_16x16x32_bf16(a0, b3, acc[0][3], 0,0,0);
    acc[1][0] = __builtin_amdgcn_mfma_f32_16x16x32_bf16(a1, b0, acc[1][0], 0,0,0);
    acc[1][1] = __builtin_amdgcn_mfma_f32_16x16x32_bf16(a1, b1, acc[1][1], 0,0,0);
    acc[1][2] = __builtin_amdgcn_mfma_f32_16x16x32_bf16(a1, b2, acc[1][2], 0,0,0);
    acc[1][3] = __builtin_amdgcn_mfma_f32_16x16x32_bf16(a1, b3, acc[1][3], 0,0,0);
  }
  // C/D layout (verified m89): col = lane&15, row = (lane>>4)*4 + reg
  #pragma unroll
  for (int mt = 0; mt < 2; ++mt){
    #pragma unroll
    for (int r = 0; r < 4; ++r){
      int m = m0 + w*32 + mt*16 + lq*4 + r;
      int orow = (EPI==3) ? remap[m] : m;
      #pragma unroll
      for (int nt = 0; nt < 4; ++nt){
        int n = n0 + nt*16 + lr;
        if (n < N){
          float v = acc[mt][nt][r] + (bias ? bias[n] : 0.f);
          if (EPI==2) v = softplus_f(v);
          C[(size_t)orow*ldc + n] = v;
        }
      }
    }
  }
}

// logits = hmid @ w2^T + b2 + gumbel ; idx = argmax (first occurrence)
__global__ __launch_bounds__(256) void k_argmax(const float* __restrict__ hmid,
    const float* __restrict__ w2, const float* __restrict__ b2,
    const float* __restrict__ gumbel, int* __restrict__ idx){
  int g = blockIdx.x*256 + threadIdx.x;
  float hm[64];
  const float4* hp = (const float4*)(hmid + (size_t)g*64);
  #pragma unroll
  for (int i = 0; i < 16; ++i){
    float4 v = hp[i];
    hm[i*4+0]=v.x; hm[i*4+1]=v.y; hm[i*4+2]=v.z; hm[i*4+3]=v.w;
  }
  float best = -INFINITY; int bi = 0;
  for (int c = 0; c < NTK; ++c){
    float s = b2[c] + gumbel[(size_t)g*NTK + c];
    #pragma unroll
    for (int j = 0; j < 64; ++j) s += hm[j]*w2[c*64+j];
    if (s > best){ best = s; bi = c; }
  }
  idx[g] = bi;
}

// stable counting sort per batch over 17 keys
__global__ __launch_bounds__(256) void k_sort(const int* __restrict__ idx,
    int* __restrict__ rmap, int* __restrict__ inv){
  int b = blockIdx.x, t = threadIdx.x;
  __shared__ int hist[NTK][256];
  __shared__ int tot[NTK];
  __shared__ int keybase[NTK];
  int keys[16];
  const int* ip = idx + b*NL + t*16;
  #pragma unroll
  for (int i = 0; i < 16; ++i) keys[i] = ip[i];
  #pragma unroll
  for (int k = 0; k < NTK; ++k){
    int c = 0;
    #pragma unroll
    for (int i = 0; i < 16; ++i) c += (keys[i]==k) ? 1 : 0;
    hist[k][t] = c;
  }
  __syncthreads();
  if (t < NTK){
    int run = 0;
    for (int j = 0; j < 256; ++j){ int v = hist[t][j]; hist[t][j] = run; run += v; }
    tot[t] = run;
  }
  __syncthreads();
  if (t == 0){
    int base = 0;
    for (int k = 0; k < NTK; ++k){ keybase[k] = base; base += tot[k]; }
  }
  __syncthreads();
  #pragma unroll
  for (int i = 0; i < 16; ++i){
    int k = keys[i];
    int cb = 0;
    #pragma unroll
    for (int j = 0; j < 16; ++j) cb += (j < i && keys[j]==k) ? 1 : 0;
    int pos = keybase[k] + hist[k][t] + cb;
    rmap[b*NL + pos] = b*NL + t*16 + i;
    inv[b*NL + t*16 + i] = pos;
  }
}

// depthwise 3x3 SAME conv + sigmoid gate; scatter rows to sorted order
__global__ __launch_bounds__(256) void k_cpe(const float* __restrict__ xi,
    const float* __restrict__ cw, const float* __restrict__ cb,
    const int* __restrict__ inv, float* __restrict__ us){
  int bl = blockIdx.x;
  int cg = bl & 3;
  int xt = (bl>>2) & 7;
  int yt = (bl>>5) & 7;
  int b  = bl >> 8;
  __shared__ float tile[10*10*96];
  int c0 = cg*96;
  for (int p = threadIdx.x; p < 10*10*96; p += 256){
    int c = p % 96; int xx = (p/96) % 10; int yy = p/960;
    int gy = yt*8 + yy - 1, gx = xt*8 + xx - 1;
    float v = 0.f;
    if (gy >= 0 && gy < NHH && gx >= 0 && gx < NWW)
      v = xi[((size_t)(b*NL + gy*NWW + gx))*NH + c0 + c];
    tile[p] = v;
  }
  __syncthreads();
  for (int p = threadIdx.x; p < 8*8*96; p += 256){
    int c = p % 96; int xx = (p/96) % 8; int yy = p/768;
    int ch = c0 + c;
    float acc = cb[ch];
    #pragma unroll
    for (int dy = 0; dy < 3; ++dy)
      #pragma unroll
      for (int dx = 0; dx < 3; ++dx)
        acc += tile[((yy+dy)*10 + (xx+dx))*96 + c] * cw[ch*9 + dy*3 + dx];
    float center = tile[((yy+1)*10 + (xx+1))*96 + c];
    float gate = 1.f/(1.f + expf(-acc));
    int l = (yt*8+yy)*NWW + xt*8+xx;
    int pos = inv[b*NL + l];
    us[((size_t)(b*NL + pos))*NH + ch] = center*gate;
  }
}

// split x_dbl into Bs, Cs (+prompt), and dts as zero-padded bf16 (K=32)
__global__ __launch_bounds__(256) void k_bc(const float* __restrict__ dbl,
    const int* __restrict__ idx, const float* __restrict__ fe,
    const int* __restrict__ gt, float* __restrict__ Bsb, float* __restrict__ Csb,
    short* __restrict__ dtsb){
  int g = blockIdx.x*256 + threadIdx.x;
  const float* dr = dbl + (size_t)g*56;
  int id = idx[g];
  int gather = gt[0];
  #pragma unroll
  for (int n = 0; n < NR; ++n) dtsb[(size_t)g*32 + n] = f2bf(dr[n]);
  #pragma unroll
  for (int n = NR; n < 32; ++n) dtsb[(size_t)g*32 + n] = 0;
  #pragma unroll
  for (int n = 0; n < NS; ++n){
    Bsb[(size_t)g*NS + n] = dr[24+n];
    float c = dr[40+n];
    if (gather != 0) c += fe[id*NS + n];
    Csb[(size_t)g*NS + n] = c;
  }
}

// decay helper: a[n] = exp(dlt*An[n]); pw path: binary powers of r (depth 5, not 15).
__device__ __forceinline__ void decay16(bool pw, float dlt, const float* An, float* a){
  if (pw){
    float r  = __expf(dlt*An[0]);
    float r2 = r*r;
    float r3 = r2*r;
    float r4 = r2*r2;
    float r8 = r4*r4;
    float r12 = r8*r4;
    a[0]=r;     a[1]=r2;     a[2]=r3;     a[3]=r4;
    a[4]=r4*r;  a[5]=r4*r2;  a[6]=r4*r3;  a[7]=r8;
    a[8]=r8*r;  a[9]=r8*r2;  a[10]=r8*r3; a[11]=r12;
    a[12]=r12*r; a[13]=r12*r2; a[14]=r12*r3; a[15]=r8*r8;
  } else {
    #pragma unroll
    for (int n = 0; n < NS; ++n) a[n] = __expf(dlt*An[n]);
  }
}
__device__ __forceinline__ bool pwcheck(const float* An){
  bool pw = true;
  #pragma unroll
  for (int n = 1; n < NS; ++n)
    pw = pw && (fabsf(An[n] - (n+1)*An[0]) <= 1e-4f*fabsf(An[n]));
  return pw;
}

// scan phase 1: per (b,chunk,d): Aprod[n] = exp(An[n]*sum(dlt)), Boff[n] = local scan end
__global__ __launch_bounds__(384) void k_scan1(const float* __restrict__ delta,
    const float* __restrict__ us, const float* __restrict__ Bsb,
    const float* __restrict__ A_logs, float* __restrict__ Aprod, float* __restrict__ Boff){
  int bc = blockIdx.x;
  int c = bc & (NCHUNKS-1);
  int b = bc >> 5;
  int d = threadIdx.x;
  __shared__ float4 Bsh[CHUNKLEN*4];   // [s][q]: B values, vector-staged & vector-read
  int base = b*NL + c*CHUNKLEN;
  {
    const float4* Bg = (const float4*)(Bsb + (size_t)base*NS);
    for (int p = d; p < CHUNKLEN*4; p += 384) Bsh[p] = Bg[p];
  }
  float An[NS];
  #pragma unroll
  for (int n = 0; n < NS; ++n) An[n] = -expf(A_logs[d*NS + n]);
  bool pw = pwcheck(An);
  float h[NS];
  #pragma unroll
  for (int n = 0; n < NS; ++n) h[n]=0.f;
  float sd = 0.f;
  __syncthreads();
  #pragma unroll 2
  for (int s = 0; s < CHUNKLEN; ++s){
    size_t gi = (size_t)(base + s)*NH + d;
    float dlt = delta[gi];
    float uv = us[gi];
    float du = dlt*uv;
    sd += dlt;
    float a[NS];
    decay16(pw, dlt, An, a);
    float bb[NS];
    #pragma unroll
    for (int q = 0; q < 4; ++q) *(float4*)&bb[4*q] = Bsh[s*4 + q];
    #pragma unroll
    for (int n = 0; n < NS; ++n) h[n] = a[n]*h[n] + du*bb[n];
  }
  // Aprod = product of per-step decays = exp(An[n] * sum dlt)  (exact identity)
  float ap[NS];
  decay16(pw, sd, An, ap);
  size_t o = ((size_t)bc*NH + d)*NS;
  #pragma unroll
  for (int n = 0; n < NS; ++n){ Aprod[o+n]=ap[n]; Boff[o+n]=h[n]; }
}

// scan phase 2: compose chunk summaries; hinit written IN PLACE into Boff
__global__ __launch_bounds__(256) void k_scan2(const float* __restrict__ Aprod,
    float* __restrict__ Boff){
  int i = blockIdx.x*256 + threadIdx.x;
  int dn = i % (NH*NS);
  int b = i / (NH*NS);
  float h = 0.f;
  for (int c = 0; c < NCHUNKS; ++c){
    size_t o = ((size_t)(b*NCHUNKS + c)*NH*NS) + dn;
    float a = Aprod[o];
    float bo = Boff[o];
    Boff[o] = h;
    h = a*h + bo;
  }
}

// scan phase 3 (hinit = Boff after k_scan2)
__global__ __launch_bounds__(384) void k_scan3(const float* __restrict__ delta,
    const float* __restrict__ Bsb, const float* __restrict__ Csb,
    const float* __restrict__ A_logs, const float* __restrict__ Ds,
    const float* __restrict__ hinit, float* __restrict__ us){
  int bc = blockIdx.x;
  int c = bc & (NCHUNKS-1);
  int b = bc >> 5;
  int d = threadIdx.x;
  __shared__ float4 Bsh[CHUNKLEN*4];
  __shared__ float4 Csh[CHUNKLEN*4];
  int base = b*NL + c*CHUNKLEN;
  {
    const float4* Bg = (const float4*)(Bsb + (size_t)base*NS);
    const float4* Cg = (const float4*)(Csb + (size_t)base*NS);
    for (int p = d; p < CHUNKLEN*4; p += 384){
      Bsh[p] = Bg[p];
      Csh[p] = Cg[p];
    }
  }
  float An[NS];
  #pragma unroll
  for (int n = 0; n < NS; ++n) An[n] = -expf(A_logs[d*NS + n]);
  bool pw = pwcheck(An);
  float h[NS];
  size_t ho = ((size_t)bc*NH + d)*NS;
  #pragma unroll
  for (int n = 0; n < NS; ++n) h[n] = hinit[ho + n];
  float Dd = Ds[d];
  __syncthreads();
  #pragma unroll 2
  for (int s = 0; s < CHUNKLEN; ++s){
    size_t gi = (size_t)(base + s)*NH + d;
    float dlt = delta[gi];
    float uv = us[gi];
    float du = dlt*uv;
    float a[NS];
    decay16(pw, dlt, An, a);
    float bb[NS], cc[NS];
    #pragma unroll
    for (int q = 0; q < 4; ++q){
      *(float4*)&bb[4*q] = Bsh[s*4 + q];
      *(float4*)&cc[4*q] = Csh[s*4 + q];
    }
    float y = 0.f;
    #pragma unroll
    for (int n = 0; n < NS; ++n){
      h[n] = a[n]*h[n] + du*bb[n];
      y += h[n]*cc[n];
    }
    us[gi] = y + uv*Dd;
  }
}

// layernorm stats over hidden (384): mean/rstd per token; one wave per token
__global__ __launch_bounds__(256) void k_lnstat(const float* __restrict__ y,
    float* __restrict__ mean, float* __restrict__ rstd){
  int g = blockIdx.x*4 + (threadIdx.x >> 6);
  int lane = threadIdx.x & 63;
  size_t ro = (size_t)g*NH;
  float v[6];
  #pragma unroll
  for (int i = 0; i < 6; ++i) v[i] = y[ro + i*64 + lane];
  float s = 0.f;
  #pragma unroll
  for (int i = 0; i < 6; ++i) s += v[i];
  #pragma unroll
  for (int off = 32; off > 0; off >>= 1) s += __shfl_xor(s, off);
  float mu = s * (1.f/NH);
  float vs = 0.f;
  #pragma unroll
  for (int i = 0; i < 6; ++i){ float d = v[i]-mu; vs += d*d; }
  #pragma unroll
  for (int off = 32; off > 0; off >>= 1) vs += __shfl_xor(vs, off);
  float rs = rsqrtf(vs*(1.f/NH) + 1e-5f);
  if (lane == 0){ mean[g] = mu; rstd[g] = rs; }
}

extern "C" void kernel_launch(void* const* d_in, const int* in_sizes, int n_in,
                              void* d_out, int out_size, void* d_ws, size_t ws_size,
                              hipStream_t stream){
  const float* x      = (const float*)d_in[0];
  const float* tw     = (const float*)d_in[1];
  const float* gumbel = (const float*)d_in[2];
  const float* embB   = (const float*)d_in[3];
  const float* rw1    = (const float*)d_in[4];
  const float* rb1    = (const float*)d_in[5];
  const float* rw2    = (const float*)d_in[6];
  const float* rb2    = (const float*)d_in[7];
  const float* inw    = (const float*)d_in[8];
  const float* inb    = (const float*)d_in[9];
  const float* cw     = (const float*)d_in[10];
  const float* cb     = (const float*)d_in[11];
  const float* xpw    = (const float*)d_in[12];
  const float* dtw    = (const float*)d_in[13];
  const float* dtb    = (const float*)d_in[14];
  const float* A_logs = (const float*)d_in[15];
  const float* Ds     = (const float*)d_in[16];
  const float* ng     = (const float*)d_in[17];
  const float* nbv    = (const float*)d_in[18];
  const float* ow     = (const float*)d_in[19];
  const float* ob     = (const float*)d_in[20];
  const int*   gt     = (const int*)d_in[23];
  float* out = (float*)d_out;

  // Workspace layout — IDENTICAL to round 3/5/6 (known-good through full harness).
  float* ws = (float*)d_ws;
  size_t o = 0;
  float* fe   = ws + o; o += 512;
  int* idx    = (int*)(ws + o); o += NTOK;   // dead after k_bc -> reused as LN mean
  int* rmap   = (int*)(ws + o); o += NTOK;
  int* inv    = (int*)(ws + o); o += NTOK;   // dead after k_cpe -> reused as LN rstd
  float* hmid = ws + o; o += (size_t)NTOK*64;   // reused as dbl (NTOK*56)
  float* xi   = ws + o; o += (size_t)NTOK*NH;   // reused as delta
  float* us   = ws + o; o += (size_t)NTOK*NH;   // u -> y (stays pre-LN; LN fused in out_proj)
  float* Bsb  = ws + o; o += (size_t)NTOK*NS;
  float* Csb  = ws + o; o += (size_t)NTOK*NS;
  float* Apr  = ws + o; o += (size_t)NB*NCHUNKS*NH*NS;  // dtsb aliases this (disjoint lifetime)
  float* Bof  = ws + o; o += (size_t)NB*NCHUNKS*NH*NS;  // becomes hinit in-place via k_scan2
  short* inwb = (short*)(ws + o); o += (NH*ND)/2;
  short* owb  = (short*)(ws + o); o += (ND*NH)/2;
  short* xpwb = (short*)(ws + o); o += (56*NH)/2 + 32;
  short* dtwb = (short*)(ws + o); o += (NH*32)/2;
  float* dbl = hmid;
  float* delta = xi;
  short* dtsb = (short*)Apr;   // NTOK*32 shorts = 4 MB, dies before scan1 writes Apr
  float* lnmean = (float*)idx; // NTOK floats, idx dead by LN time
  float* lnrstd = (float*)inv; // NTOK floats, inv dead by LN time

  k_emb<<<1,256,0,stream>>>(embB, tw, fe);
  k_cvtw<<<64,256,0,stream>>>(inw, ow, xpw, dtw, inwb, owb, xpwb, dtwb);
  // routing MLP layer 1 (fp32: argmax margins too tight for bf16)
  k_gemm<1><<<dim3(NTOK/64,1),256,0,stream>>>(x, ND, rw1, ND, rb1, hmid, 64, 64, ND);
  k_argmax<<<NTOK/256,256,0,stream>>>(hmid, rw2, rb2, gumbel, idx);
  k_sort<<<NB,256,0,stream>>>(idx, rmap, inv);
  // in_proj: xi = x @ inw^T + inb (bf16 MFMA, fp32 A converted in staging)
  k_mfma<0,1,0><<<dim3(NTOK/128,6),256,0,stream>>>(x, ND, inwb, ND, inb, xi, NH, NH, ND,
      nullptr, nullptr, nullptr, nullptr, nullptr);
  // CPE gate + scatter to sorted order
  k_cpe<<<NB*64*4,256,0,stream>>>(xi, cw, cb, inv, us);
  // x_dbl = us @ xpw^T (bf16 MFMA, N=56)
  k_mfma<0,1,0><<<dim3(NTOK/128,1),256,0,stream>>>(us, NH, xpwb, NH, nullptr, dbl, 56, 56, NH,
      nullptr, nullptr, nullptr, nullptr, nullptr);
  k_bc<<<NTOK/256,256,0,stream>>>(dbl, idx, fe, gt, Bsb, Csb, dtsb);
  // delta = softplus(dts @ dtw^T + dtb)  (bf16 MFMA, K=32 padded)
  k_mfma<2,0,0><<<dim3(NTOK/128,6),256,0,stream>>>(dtsb, 32, dtwb, 32, dtb, delta, NH, NH, 32,
      nullptr, nullptr, nullptr, nullptr, nullptr);
  k_scan1<<<NB*NCHUNKS,384,0,stream>>>(delta, us, Bsb, A_logs, Apr, Bof);
  k_scan2<<<(NB*NH*NS)/256,256,0,stream>>>(Apr, Bof);
  k_scan3<<<NB*NCHUNKS,384,0,stream>>>(delta, Bsb, Csb, A_logs, Ds, Bof, us);
  // layernorm stats only; normalization fused into out_proj A-staging
  k_lnstat<<<NTOK/4,256,0,stream>>>(us, lnmean, lnrstd);
  // out_proj (+fused LN) + scatter back to original token order
  k_mfma<3,1,1><<<dim3(NTOK/128,3),256,0,stream>>>(us, NH, owb, NH, ob, out, ND, ND, NH,
      rmap, lnmean, lnrstd, ng, nbv);
}

// Round 8
// 726.083 us; speedup vs baseline: 1.4722x; 1.0445x over previous
//
#include <hip/hip_runtime.h>
#include <math.h>

#define NB 16
#define NL 4096
#define ND 192
#define NH 384
#define NS 16
#define NTK 17
#define NIR 128
#define NR 24
#define NHH 64
#define NWW 64
#define NCHUNKS 32
#define CHUNKLEN 128
#define NTOK (NB*NL)

typedef __attribute__((ext_vector_type(8))) short short8;
typedef __attribute__((ext_vector_type(4))) float floatx4;

__device__ __forceinline__ float gelu_tanh(float x){
  return 0.5f*x*(1.0f + tanhf(0.7978845608028654f*(x + 0.044715f*x*x*x)));
}
__device__ __forceinline__ float softplus_f(float x){
  return (x > 20.0f) ? x : log1pf(expf(x));
}
__device__ __forceinline__ short f2bf(float f){
  unsigned u = __float_as_uint(f);
  unsigned r = (u + 0x7fffu + ((u >> 16) & 1u)) >> 16;
  return (short)r;
}

union Pack8 { uint4 v; short s[8]; };

// full_emb = embB(17x128) @ token_weight(128x16)
__global__ void k_emb(const float* __restrict__ embB, const float* __restrict__ tw,
                      float* __restrict__ fe){
  for (int o = threadIdx.x; o < NTK*NS; o += 256){
    int t = o / NS, s = o % NS;
    float acc = 0.f;
    for (int i = 0; i < NIR; ++i) acc += embB[t*NIR+i]*tw[i*NS+s];
    fe[o] = acc;
  }
}

// convert weights to bf16 (dtw zero-padded K 24->32)
__global__ void k_cvtw(const float* __restrict__ inw, const float* __restrict__ ow,
                       const float* __restrict__ xpw, const float* __restrict__ dtw,
                       short* __restrict__ inwb, short* __restrict__ owb,
                       short* __restrict__ xpwb, short* __restrict__ dtwb){
  int i = blockIdx.x*256 + threadIdx.x;
  int stride = gridDim.x*256;
  for (int p = i; p < NH*ND; p += stride) inwb[p] = f2bf(inw[p]);
  for (int p = i; p < ND*NH; p += stride) owb[p] = f2bf(ow[p]);
  for (int p = i; p < 56*NH; p += stride) xpwb[p] = f2bf(xpw[p]);
  for (int p = i; p < NH*32; p += stride){
    int r = p >> 5, c = p & 31;
    dtwb[p] = (c < NR) ? f2bf(dtw[r*NR + c]) : (short)0;
  }
}

// fp32 GEMM (routing layer only: argmax sensitivity forbids bf16 here)
template<int EPI>
__global__ __launch_bounds__(256) void k_gemm(const float* __restrict__ A, int lda,
    const float* __restrict__ W, int ldw, const float* __restrict__ bias,
    float* __restrict__ C, int ldc, int N, int K){
  __shared__ float As[16][68];
  __shared__ float Ws[16][68];
  int tid = threadIdx.x;
  int m0 = blockIdx.x*64, n0 = blockIdx.y*64;
  int tx = tid & 15, ty = tid >> 4;
  int srow = tid >> 2, skseg = (tid & 3)*4;
  float acc[4][4] = {};
  for (int k0 = 0; k0 < K; k0 += 16){
    {
      const float* ap = A + (size_t)(m0+srow)*lda + k0 + skseg;
      float4 v = *(const float4*)ap;
      As[skseg+0][srow]=v.x; As[skseg+1][srow]=v.y;
      As[skseg+2][srow]=v.z; As[skseg+3][srow]=v.w;
    }
    {
      float4 v = {0.f,0.f,0.f,0.f};
      if (n0 + srow < N) v = *(const float4*)(W + (size_t)(n0+srow)*ldw + k0 + skseg);
      Ws[skseg+0][srow]=v.x; Ws[skseg+1][srow]=v.y;
      Ws[skseg+2][srow]=v.z; Ws[skseg+3][srow]=v.w;
    }
    __syncthreads();
    #pragma unroll
    for (int kk = 0; kk < 16; ++kk){
      float4 av = *(const float4*)&As[kk][ty*4];
      float4 wv = *(const float4*)&Ws[kk][tx*4];
      acc[0][0] += av.x*wv.x; acc[0][1] += av.x*wv.y;
      acc[0][2] += av.x*wv.z; acc[0][3] += av.x*wv.w;
      acc[1][0] += av.y*wv.x; acc[1][1] += av.y*wv.y;
      acc[1][2] += av.y*wv.z; acc[1][3] += av.y*wv.w;
      acc[2][0] += av.z*wv.x; acc[2][1] += av.z*wv.y;
      acc[2][2] += av.z*wv.z; acc[2][3] += av.z*wv.w;
      acc[3][0] += av.w*wv.x; acc[3][1] += av.w*wv.y;
      acc[3][2] += av.w*wv.z; acc[3][3] += av.w*wv.w;
    }
    __syncthreads();
  }
  #pragma unroll
  for (int i = 0; i < 4; ++i){
    int m = m0 + ty*4 + i;
    #pragma unroll
    for (int j = 0; j < 4; ++j){
      int n = n0 + tx*4 + j;
      if (n < N){
        float v = acc[i][j] + (bias ? bias[n] : 0.f);
        if (EPI==1) v = gelu_tanh(v);
        C[(size_t)m*ldc + n] = v;
      }
    }
  }
}

// bf16 MFMA GEMM: C(MxN) = A(MxK) @ W(NxK bf16)^T + bias.
// A fp32 (AF32=1, converted during LDS staging) or bf16 (AF32=0).
// LNA=1: apply per-row layernorm (mean/rstd precomputed; g/b over K) during staging.
// EPI: 0 none, 2 softplus, 3 row-scatter via remap
template<int EPI, int AF32, int LNA>
__global__ __launch_bounds__(256) void k_mfma(const void* __restrict__ Aptr, int lda,
    const short* __restrict__ Wbf, int ldw, const float* __restrict__ bias,
    float* __restrict__ C, int ldc, int N, int K, const int* __restrict__ remap,
    const float* __restrict__ lnm, const float* __restrict__ lnr,
    const float* __restrict__ lng, const float* __restrict__ lnb){
  __shared__ short As[128*40];   // stride 40 shorts = 80B: 16B-aligned b128, 2-way banks (free)
  __shared__ short Bs[64*40];
  int tid = threadIdx.x;
  int m0 = blockIdx.x*128, n0 = blockIdx.y*64;
  int w = tid >> 6, lane = tid & 63;
  int lq = lane >> 4, lr = lane & 15;
  floatx4 acc[2][4];
  #pragma unroll
  for (int i = 0; i < 2; ++i)
    #pragma unroll
    for (int j = 0; j < 4; ++j) acc[i][j] = (floatx4){0.f,0.f,0.f,0.f};
  int ar = tid >> 1, aq = (tid & 1)*2;   // A: each thread stages 16 elts of one row
  int br = tid >> 2, bq = tid & 3;       // B: each thread stages 8 elts of one row
  float mr = 0.f, rr = 0.f;
  if (LNA){ mr = lnm[m0+ar]; rr = lnr[m0+ar]; }
  for (int k0 = 0; k0 < K; k0 += 32){
    Pack8 sa0, sa1;
    if (AF32){
      const float* ap = (const float*)Aptr + (size_t)(m0+ar)*lda + k0 + aq*8;
      float f[16];
      float4 f0 = *(const float4*)(ap);
      float4 f1 = *(const float4*)(ap+4);
      float4 f2 = *(const float4*)(ap+8);
      float4 f3 = *(const float4*)(ap+12);
      f[0]=f0.x; f[1]=f0.y; f[2]=f0.z; f[3]=f0.w;
      f[4]=f1.x; f[5]=f1.y; f[6]=f1.z; f[7]=f1.w;
      f[8]=f2.x; f[9]=f2.y; f[10]=f2.z; f[11]=f2.w;
      f[12]=f3.x; f[13]=f3.y; f[14]=f3.z; f[15]=f3.w;
      if (LNA){
        const float* gp = lng + k0 + aq*8;
        const float* bp = lnb + k0 + aq*8;
        #pragma unroll
        for (int j = 0; j < 16; ++j) f[j] = (f[j]-mr)*rr*gp[j] + bp[j];
      }
      #pragma unroll
      for (int j = 0; j < 8; ++j){ sa0.s[j] = f2bf(f[j]); sa1.s[j] = f2bf(f[8+j]); }
    } else {
      const short* ap = (const short*)Aptr + (size_t)(m0+ar)*lda + k0 + aq*8;
      sa0.v = *(const uint4*)ap;
      sa1.v = *(const uint4*)(ap + 8);
    }
    uint4 bv = {0u,0u,0u,0u};
    if (n0 + br < N) bv = *(const uint4*)(Wbf + (size_t)(n0+br)*ldw + k0 + bq*8);
    __syncthreads();
    *(uint4*)&As[ar*40 + aq*8]     = sa0.v;
    *(uint4*)&As[ar*40 + aq*8 + 8] = sa1.v;
    *(uint4*)&Bs[br*40 + bq*8]     = bv;
    __syncthreads();
    short8 a0 = *(const short8*)&As[(w*32      + lr)*40 + lq*8];
    short8 a1 = *(const short8*)&As[(w*32 + 16 + lr)*40 + lq*8];
    short8 b0 = *(const short8*)&Bs[(     lr)*40 + lq*8];
    short8 b1 = *(const short8*)&Bs[(16 + lr)*40 + lq*8];
    short8 b2 = *(const short8*)&Bs[(32 + lr)*40 + lq*8];
    short8 b3 = *(const short8*)&Bs[(48 + lr)*40 + lq*8];
    acc[0][0] = __builtin_amdgcn_mfma_f32_16x16x32_bf16(a0, b0, acc[0][0], 0,0,0);
    acc[0][1] = __builtin_amdgcn_mfma_f32_16x16x32_bf16(a0, b1, acc[0][1], 0,0,0);
    acc[0][2] = __builtin_amdgcn_mfma_f32_16x16x32_bf16(a0, b2, acc[0][2], 0,0,0);
    acc[0][3] = __builtin_amdgcn_mfma_f32_16x16x32_bf16(a0, b3, acc[0][3], 0,0,0);
    acc[1][0] = __builtin_amdgcn_mfma_f32_16x16x32_bf16(a1, b0, acc[1][0], 0,0,0);
    acc[1][1] = __builtin_amdgcn_mfma_f32_16x16x32_bf16(a1, b1, acc[1][1], 0,0,0);
    acc[1][2] = __builtin_amdgcn_mfma_f32_16x16x32_bf16(a1, b2, acc[1][2], 0,0,0);
    acc[1][3] = __builtin_amdgcn_mfma_f32_16x16x32_bf16(a1, b3, acc[1][3], 0,0,0);
  }
  // C/D layout (verified m89): col = lane&15, row = (lane>>4)*4 + reg
  #pragma unroll
  for (int mt = 0; mt < 2; ++mt){
    #pragma unroll
    for (int r = 0; r < 4; ++r){
      int m = m0 + w*32 + mt*16 + lq*4 + r;
      int orow = (EPI==3) ? remap[m] : m;
      #pragma unroll
      for (int nt = 0; nt < 4; ++nt){
        int n = n0 + nt*16 + lr;
        if (n < N){
          float v = acc[mt][nt][r] + (bias ? bias[n] : 0.f);
          if (EPI==2) v = softplus_f(v);
          C[(size_t)orow*ldc + n] = v;
        }
      }
    }
  }
}

// logits = hmid @ w2^T + b2 + gumbel ; idx = argmax (first occurrence)
__global__ __launch_bounds__(256) void k_argmax(const float* __restrict__ hmid,
    const float* __restrict__ w2, const float* __restrict__ b2,
    const float* __restrict__ gumbel, int* __restrict__ idx){
  int g = blockIdx.x*256 + threadIdx.x;
  float hm[64];
  const float4* hp = (const float4*)(hmid + (size_t)g*64);
  #pragma unroll
  for (int i = 0; i < 16; ++i){
    float4 v = hp[i];
    hm[i*4+0]=v.x; hm[i*4+1]=v.y; hm[i*4+2]=v.z; hm[i*4+3]=v.w;
  }
  float best = -INFINITY; int bi = 0;
  for (int c = 0; c < NTK; ++c){
    float s = b2[c] + gumbel[(size_t)g*NTK + c];
    #pragma unroll
    for (int j = 0; j < 64; ++j) s += hm[j]*w2[c*64+j];
    if (s > best){ best = s; bi = c; }
  }
  idx[g] = bi;
}

// stable counting sort per batch over 17 keys
__global__ __launch_bounds__(256) void k_sort(const int* __restrict__ idx,
    int* __restrict__ rmap, int* __restrict__ inv){
  int b = blockIdx.x, t = threadIdx.x;
  __shared__ int hist[NTK][256];
  __shared__ int tot[NTK];
  __shared__ int keybase[NTK];
  int keys[16];
  const int* ip = idx + b*NL + t*16;
  #pragma unroll
  for (int i = 0; i < 16; ++i) keys[i] = ip[i];
  #pragma unroll
  for (int k = 0; k < NTK; ++k){
    int c = 0;
    #pragma unroll
    for (int i = 0; i < 16; ++i) c += (keys[i]==k) ? 1 : 0;
    hist[k][t] = c;
  }
  __syncthreads();
  if (t < NTK){
    int run = 0;
    for (int j = 0; j < 256; ++j){ int v = hist[t][j]; hist[t][j] = run; run += v; }
    tot[t] = run;
  }
  __syncthreads();
  if (t == 0){
    int base = 0;
    for (int k = 0; k < NTK; ++k){ keybase[k] = base; base += tot[k]; }
  }
  __syncthreads();
  #pragma unroll
  for (int i = 0; i < 16; ++i){
    int k = keys[i];
    int cb = 0;
    #pragma unroll
    for (int j = 0; j < 16; ++j) cb += (j < i && keys[j]==k) ? 1 : 0;
    int pos = keybase[k] + hist[k][t] + cb;
    rmap[b*NL + pos] = b*NL + t*16 + i;
    inv[b*NL + t*16 + i] = pos;
  }
}

// depthwise 3x3 SAME conv + sigmoid gate; scatter rows to sorted order.
// Block (96,4): threadIdx.x IS the channel -> zero integer div/mod anywhere.
__global__ __launch_bounds__(384) void k_cpe(const float* __restrict__ xi,
    const float* __restrict__ cw, const float* __restrict__ cb,
    const int* __restrict__ inv, float* __restrict__ us){
  int bl = blockIdx.x;
  int cg = bl & 3;
  int xt = (bl>>2) & 7;
  int yt = (bl>>5) & 7;
  int b  = bl >> 8;
  __shared__ float tile[10*10*96];   // [yy][xx][c], c contiguous
  int tx = threadIdx.x;              // channel within group (0..95)
  int ty = threadIdx.y;              // spatial worker (0..3)
  int c0 = cg*96;
  int ch = c0 + tx;
  // stage 10x10 halo tile, c-major coalesced, no divisions
  for (int yy = 0; yy < 10; ++yy){
    int gy = yt*8 + yy - 1;
    for (int xx = ty; xx < 10; xx += 4){
      int gx = xt*8 + xx - 1;
      float v = 0.f;
      if (gy >= 0 && gy < NHH && gx >= 0 && gx < NWW)
        v = xi[((size_t)(b*NL + gy*NWW + gx))*NH + ch];
      tile[(yy*10 + xx)*96 + tx] = v;
    }
  }
  // conv weights fixed per thread: hoist to registers
  float wreg[9];
  #pragma unroll
  for (int j = 0; j < 9; ++j) wreg[j] = cw[ch*9 + j];
  float bias = cb[ch];
  __syncthreads();
  for (int yy = ty; yy < 8; yy += 4){
    #pragma unroll
    for (int xx = 0; xx < 8; ++xx){
      float acc = bias;
      #pragma unroll
      for (int dy = 0; dy < 3; ++dy)
        #pragma unroll
        for (int dx = 0; dx < 3; ++dx)
          acc += tile[((yy+dy)*10 + (xx+dx))*96 + tx] * wreg[dy*3+dx];
      float center = tile[((yy+1)*10 + (xx+1))*96 + tx];
      float gate = 1.f/(1.f + expf(-acc));
      int l = (yt*8+yy)*NWW + xt*8+xx;
      int pos = inv[b*NL + l];
      us[((size_t)(b*NL + pos))*NH + ch] = center*gate;
    }
  }
}

// split x_dbl into Bs, Cs (+prompt), and dts as zero-padded bf16 (K=32)
__global__ __launch_bounds__(256) void k_bc(const float* __restrict__ dbl,
    const int* __restrict__ idx, const float* __restrict__ fe,
    const int* __restrict__ gt, float* __restrict__ Bsb, float* __restrict__ Csb,
    short* __restrict__ dtsb){
  int g = blockIdx.x*256 + threadIdx.x;
  const float* dr = dbl + (size_t)g*56;
  int id = idx[g];
  int gather = gt[0];
  #pragma unroll
  for (int n = 0; n < NR; ++n) dtsb[(size_t)g*32 + n] = f2bf(dr[n]);
  #pragma unroll
  for (int n = NR; n < 32; ++n) dtsb[(size_t)g*32 + n] = 0;
  #pragma unroll
  for (int n = 0; n < NS; ++n){
    Bsb[(size_t)g*NS + n] = dr[24+n];
    float c = dr[40+n];
    if (gather != 0) c += fe[id*NS + n];
    Csb[(size_t)g*NS + n] = c;
  }
}

// decay helper: a[n] = exp(dlt*An[n]); pw path: binary powers of r (depth 5, not 15).
__device__ __forceinline__ void decay16(bool pw, float dlt, const float* An, float* a){
  if (pw){
    float r  = __expf(dlt*An[0]);
    float r2 = r*r;
    float r3 = r2*r;
    float r4 = r2*r2;
    float r8 = r4*r4;
    float r12 = r8*r4;
    a[0]=r;     a[1]=r2;     a[2]=r3;     a[3]=r4;
    a[4]=r4*r;  a[5]=r4*r2;  a[6]=r4*r3;  a[7]=r8;
    a[8]=r8*r;  a[9]=r8*r2;  a[10]=r8*r3; a[11]=r12;
    a[12]=r12*r; a[13]=r12*r2; a[14]=r12*r3; a[15]=r8*r8;
  } else {
    #pragma unroll
    for (int n = 0; n < NS; ++n) a[n] = __expf(dlt*An[n]);
  }
}
__device__ __forceinline__ bool pwcheck(const float* An){
  bool pw = true;
  #pragma unroll
  for (int n = 1; n < NS; ++n)
    pw = pw && (fabsf(An[n] - (n+1)*An[0]) <= 1e-4f*fabsf(An[n]));
  return pw;
}

// scan phase 1: per (b,chunk,d): Aprod[n] = exp(An[n]*sum(dlt)), Boff[n] = local scan end
__global__ __launch_bounds__(384) void k_scan1(const float* __restrict__ delta,
    const float* __restrict__ us, const float* __restrict__ Bsb,
    const float* __restrict__ A_logs, float* __restrict__ Aprod, float* __restrict__ Boff){
  int bc = blockIdx.x;
  int c = bc & (NCHUNKS-1);
  int b = bc >> 5;
  int d = threadIdx.x;
  __shared__ float4 Bsh[CHUNKLEN*4];
  int base = b*NL + c*CHUNKLEN;
  {
    const float4* Bg = (const float4*)(Bsb + (size_t)base*NS);
    for (int p = d; p < CHUNKLEN*4; p += 384) Bsh[p] = Bg[p];
  }
  float An[NS];
  #pragma unroll
  for (int n = 0; n < NS; ++n) An[n] = -expf(A_logs[d*NS + n]);
  bool pw = pwcheck(An);
  float h[NS];
  #pragma unroll
  for (int n = 0; n < NS; ++n) h[n]=0.f;
  float sd = 0.f;
  __syncthreads();
  size_t gi = (size_t)base*NH + d;
  float dlt = delta[gi];
  float uv  = us[gi];
  #pragma unroll 2
  for (int s = 0; s < CHUNKLEN; ++s){
    float dltc = dlt, uvc = uv;
    if (s < CHUNKLEN-1){            // prefetch next step
      dlt = delta[gi + NH];
      uv  = us[gi + NH];
    }
    float du = dltc*uvc;
    sd += dltc;
    float a[NS];
    decay16(pw, dltc, An, a);
    float bb[NS];
    #pragma unroll
    for (int q = 0; q < 4; ++q) *(float4*)&bb[4*q] = Bsh[s*4 + q];
    #pragma unroll
    for (int n = 0; n < NS; ++n) h[n] = a[n]*h[n] + du*bb[n];
    gi += NH;
  }
  // Aprod = product of per-step decays = exp(An[n] * sum dlt)  (exact identity)
  float ap[NS];
  decay16(pw, sd, An, ap);
  size_t o = ((size_t)bc*NH + d)*NS;
  #pragma unroll
  for (int n = 0; n < NS; ++n){ Aprod[o+n]=ap[n]; Boff[o+n]=h[n]; }
}

// scan phase 2: compose chunk summaries; hinit written IN PLACE into Boff
__global__ __launch_bounds__(256) void k_scan2(const float* __restrict__ Aprod,
    float* __restrict__ Boff){
  int i = blockIdx.x*256 + threadIdx.x;
  int dn = i % (NH*NS);
  int b = i / (NH*NS);
  float h = 0.f;
  for (int c = 0; c < NCHUNKS; ++c){
    size_t o = ((size_t)(b*NCHUNKS + c)*NH*NS) + dn;
    float a = Aprod[o];
    float bo = Boff[o];
    Boff[o] = h;
    h = a*h + bo;
  }
}

// scan phase 3 (hinit = Boff after k_scan2)
__global__ __launch_bounds__(384) void k_scan3(const float* __restrict__ delta,
    const float* __restrict__ Bsb, const float* __restrict__ Csb,
    const float* __restrict__ A_logs, const float* __restrict__ Ds,
    const float* __restrict__ hinit, float* __restrict__ us){
  int bc = blockIdx.x;
  int c = bc & (NCHUNKS-1);
  int b = bc >> 5;
  int d = threadIdx.x;
  __shared__ float4 Bsh[CHUNKLEN*4];
  __shared__ float4 Csh[CHUNKLEN*4];
  int base = b*NL + c*CHUNKLEN;
  {
    const float4* Bg = (const float4*)(Bsb + (size_t)base*NS);
    const float4* Cg = (const float4*)(Csb + (size_t)base*NS);
    for (int p = d; p < CHUNKLEN*4; p += 384){
      Bsh[p] = Bg[p];
      Csh[p] = Cg[p];
    }
  }
  float An[NS];
  #pragma unroll
  for (int n = 0; n < NS; ++n) An[n] = -expf(A_logs[d*NS + n]);
  bool pw = pwcheck(An);
  float h[NS];
  size_t ho = ((size_t)bc*NH + d)*NS;
  #pragma unroll
  for (int n = 0; n < NS; ++n) h[n] = hinit[ho + n];
  float Dd = Ds[d];
  __syncthreads();
  size_t gi = (size_t)base*NH + d;
  float dlt = delta[gi];
  float uv  = us[gi];
  #pragma unroll 2
  for (int s = 0; s < CHUNKLEN; ++s){
    float dltc = dlt, uvc = uv;
    if (s < CHUNKLEN-1){            // prefetch next step
      dlt = delta[gi + NH];
      uv  = us[gi + NH];
    }
    float du = dltc*uvc;
    float a[NS];
    decay16(pw, dltc, An, a);
    float bb[NS], cc[NS];
    #pragma unroll
    for (int q = 0; q < 4; ++q){
      *(float4*)&bb[4*q] = Bsh[s*4 + q];
      *(float4*)&cc[4*q] = Csh[s*4 + q];
    }
    float y = 0.f;
    #pragma unroll
    for (int n = 0; n < NS; ++n){
      h[n] = a[n]*h[n] + du*bb[n];
      y += h[n]*cc[n];
    }
    us[gi] = y + uvc*Dd;
    gi += NH;
  }
}

// layernorm stats over hidden (384): mean/rstd per token; one wave per token
__global__ __launch_bounds__(256) void k_lnstat(const float* __restrict__ y,
    float* __restrict__ mean, float* __restrict__ rstd){
  int g = blockIdx.x*4 + (threadIdx.x >> 6);
  int lane = threadIdx.x & 63;
  size_t ro = (size_t)g*NH;
  float v[6];
  #pragma unroll
  for (int i = 0; i < 6; ++i) v[i] = y[ro + i*64 + lane];
  float s = 0.f;
  #pragma unroll
  for (int i = 0; i < 6; ++i) s += v[i];
  #pragma unroll
  for (int off = 32; off > 0; off >>= 1) s += __shfl_xor(s, off);
  float mu = s * (1.f/NH);
  float vs = 0.f;
  #pragma unroll
  for (int i = 0; i < 6; ++i){ float d = v[i]-mu; vs += d*d; }
  #pragma unroll
  for (int off = 32; off > 0; off >>= 1) vs += __shfl_xor(vs, off);
  float rs = rsqrtf(vs*(1.f/NH) + 1e-5f);
  if (lane == 0){ mean[g] = mu; rstd[g] = rs; }
}

extern "C" void kernel_launch(void* const* d_in, const int* in_sizes, int n_in,
                              void* d_out, int out_size, void* d_ws, size_t ws_size,
                              hipStream_t stream){
  const float* x      = (const float*)d_in[0];
  const float* tw     = (const float*)d_in[1];
  const float* gumbel = (const float*)d_in[2];
  const float* embB   = (const float*)d_in[3];
  const float* rw1    = (const float*)d_in[4];
  const float* rb1    = (const float*)d_in[5];
  const float* rw2    = (const float*)d_in[6];
  const float* rb2    = (const float*)d_in[7];
  const float* inw    = (const float*)d_in[8];
  const float* inb    = (const float*)d_in[9];
  const float* cw     = (const float*)d_in[10];
  const float* cb     = (const float*)d_in[11];
  const float* xpw    = (const float*)d_in[12];
  const float* dtw    = (const float*)d_in[13];
  const float* dtb    = (const float*)d_in[14];
  const float* A_logs = (const float*)d_in[15];
  const float* Ds     = (const float*)d_in[16];
  const float* ng     = (const float*)d_in[17];
  const float* nbv    = (const float*)d_in[18];
  const float* ow     = (const float*)d_in[19];
  const float* ob     = (const float*)d_in[20];
  const int*   gt     = (const int*)d_in[23];
  float* out = (float*)d_out;

  // Workspace layout — IDENTICAL to round 3/5/6/7 (known-good through full harness).
  float* ws = (float*)d_ws;
  size_t o = 0;
  float* fe   = ws + o; o += 512;
  int* idx    = (int*)(ws + o); o += NTOK;   // dead after k_bc -> reused as LN mean
  int* rmap   = (int*)(ws + o); o += NTOK;
  int* inv    = (int*)(ws + o); o += NTOK;   // dead after k_cpe -> reused as LN rstd
  float* hmid = ws + o; o += (size_t)NTOK*64;   // reused as dbl (NTOK*56)
  float* xi   = ws + o; o += (size_t)NTOK*NH;   // reused as delta
  float* us   = ws + o; o += (size_t)NTOK*NH;   // u -> y (stays pre-LN; LN fused in out_proj)
  float* Bsb  = ws + o; o += (size_t)NTOK*NS;
  float* Csb  = ws + o; o += (size_t)NTOK*NS;
  float* Apr  = ws + o; o += (size_t)NB*NCHUNKS*NH*NS;  // dtsb aliases this (disjoint lifetime)
  float* Bof  = ws + o; o += (size_t)NB*NCHUNKS*NH*NS;  // becomes hinit in-place via k_scan2
  short* inwb = (short*)(ws + o); o += (NH*ND)/2;
  short* owb  = (short*)(ws + o); o += (ND*NH)/2;
  short* xpwb = (short*)(ws + o); o += (56*NH)/2 + 32;
  short* dtwb = (short*)(ws + o); o += (NH*32)/2;
  float* dbl = hmid;
  float* delta = xi;
  short* dtsb = (short*)Apr;   // NTOK*32 shorts = 4 MB, dies before scan1 writes Apr
  float* lnmean = (float*)idx; // NTOK floats, idx dead by LN time
  float* lnrstd = (float*)inv; // NTOK floats, inv dead by LN time

  k_emb<<<1,256,0,stream>>>(embB, tw, fe);
  k_cvtw<<<64,256,0,stream>>>(inw, ow, xpw, dtw, inwb, owb, xpwb, dtwb);
  // routing MLP layer 1 (fp32: argmax margins too tight for bf16)
  k_gemm<1><<<dim3(NTOK/64,1),256,0,stream>>>(x, ND, rw1, ND, rb1, hmid, 64, 64, ND);
  k_argmax<<<NTOK/256,256,0,stream>>>(hmid, rw2, rb2, gumbel, idx);
  k_sort<<<NB,256,0,stream>>>(idx, rmap, inv);
  // in_proj: xi = x @ inw^T + inb (bf16 MFMA, fp32 A converted in staging)
  k_mfma<0,1,0><<<dim3(NTOK/128,6),256,0,stream>>>(x, ND, inwb, ND, inb, xi, NH, NH, ND,
      nullptr, nullptr, nullptr, nullptr, nullptr);
  // CPE gate + scatter to sorted order (div-free block: (96,4))
  k_cpe<<<NB*64*4,dim3(96,4),0,stream>>>(xi, cw, cb, inv, us);
  // x_dbl = us @ xpw^T (bf16 MFMA, N=56)
  k_mfma<0,1,0><<<dim3(NTOK/128,1),256,0,stream>>>(us, NH, xpwb, NH, nullptr, dbl, 56, 56, NH,
      nullptr, nullptr, nullptr, nullptr, nullptr);
  k_bc<<<NTOK/256,256,0,stream>>>(dbl, idx, fe, gt, Bsb, Csb, dtsb);
  // delta = softplus(dts @ dtw^T + dtb)  (bf16 MFMA, K=32 padded)
  k_mfma<2,0,0><<<dim3(NTOK/128,6),256,0,stream>>>(dtsb, 32, dtwb, 32, dtb, delta, NH, NH, 32,
      nullptr, nullptr, nullptr, nullptr, nullptr);
  k_scan1<<<NB*NCHUNKS,384,0,stream>>>(delta, us, Bsb, A_logs, Apr, Bof);
  k_scan2<<<(NB*NH*NS)/256,256,0,stream>>>(Apr, Bof);
  k_scan3<<<NB*NCHUNKS,384,0,stream>>>(delta, Bsb, Csb, A_logs, Ds, Bof, us);
  // layernorm stats only; normalization fused into out_proj A-staging
  k_lnstat<<<NTOK/4,256,0,stream>>>(us, lnmean, lnrstd);
  // out_proj (+fused LN) + scatter back to original token order
  k_mfma<3,1,1><<<dim3(NTOK/128,3),256,0,stream>>>(us, NH, owb, NH, ob, out, ND, ND, NH,
      rmap, lnmean, lnrstd, ng, nbv);
}